// Round 1
// baseline (3256.364 us; speedup 1.0000x reference)
//
#include <hip/hip_runtime.h>
#include <cstddef>

#define NE 100000   // entities
#define EN 4096     // new edges
#define ET 254096   // total edges
#define D 128       // D_ENT
#define DR 64       // D_REL
#define NR 9        // relations
#define NT 3        // node types
#define NI 8        // intents
#define CHUNK 2048  // edges scanned per block

__device__ __forceinline__ float wave_sum(float v) {
#pragma unroll
  for (int off = 32; off; off >>= 1) v += __shfl_xor(v, off, 64);
  return v;
}

__global__ void fill_zero(float4* __restrict__ p, int n4) {
  int i = blockIdx.x * blockDim.x + threadIdx.x;
  if (i < n4) p[i] = make_float4(0.f, 0.f, 0.f, 0.f);
}

__global__ void k_init(float* __restrict__ ent, const int* __restrict__ ntypes,
                       const float* __restrict__ def, const float* __restrict__ emb) {
  int i = blockIdx.x * blockDim.x + threadIdx.x;
  const int n = NE * (D / 4);
  if (i >= n) return;
  int row = i >> 5;  // D/4 = 32 float4 per row
  int c = i & 31;
  float4 v;
  if (row < EN) {
    int t = ntypes[row];
    v = ((const float4*)(def + t * D))[c];
  } else {
    v = ((const float4*)(emb + (size_t)(row - EN) * D))[c];
  }
  ((float4*)(ent + (size_t)row * D))[c] = v;
}

// Kernel A: per-edge attention scores -> exp_s, denom (segment sum).
// Blocks specialized per relation (blockIdx.y), W_rel[r] + all W_intent in LDS.
__global__ __launch_bounds__(256) void k_scores(
    const float* __restrict__ ent,
    const int* __restrict__ nedg, const int* __restrict__ sedg,
    const float* __restrict__ rel_emb,
    const float* __restrict__ W_rel, const float* __restrict__ b_rel,
    const float* __restrict__ W_int, const float* __restrict__ b_int,
    const float* __restrict__ W_ibn, const float* __restrict__ b_ibn,
    float* __restrict__ exps, float* __restrict__ denom) {
  const int r = blockIdx.y;
  __shared__ float lWrel[D * DR];        // 32 KB
  __shared__ float lWintT[NT * NI * D];  // 12 KB, transposed [tt][j][i]
  __shared__ float lbint[NT * NI];
  __shared__ float lWibn[NT * NI * NR];
  __shared__ float lbibn[NT * NR];
  __shared__ float lbrel[DR];
  __shared__ float lrele[DR];
  __shared__ float lsrc[4][D];  // per-wave src staging

  const int tid = threadIdx.x;
  for (int i = tid; i < D * DR; i += 256) lWrel[i] = W_rel[r * D * DR + i];
  for (int i = tid; i < NT * D * NI; i += 256) {
    int tt = i / (D * NI), rem = i % (D * NI), row = rem / NI, j = rem % NI;
    lWintT[(tt * NI + j) * D + row] = W_int[i];  // transpose for conflict-free reads
  }
  for (int i = tid; i < NT * NI; i += 256) lbint[i] = b_int[i];
  for (int i = tid; i < NT * NI * NR; i += 256) lWibn[i] = W_ibn[i];
  for (int i = tid; i < NT * NR; i += 256) lbibn[i] = b_ibn[i];
  if (tid < DR) {
    lbrel[tid] = b_rel[r * DR + tid];
    lrele[tid] = rel_emb[r * DR + tid];
  }
  __syncthreads();

  const int lane = tid & 63;
  const int wv = tid >> 6;
  const int base = blockIdx.x * CHUNK;

  for (int g = wv; g < CHUNK / 64; g += 4) {
    const int e0 = base + g * 64;
    const int e = e0 + lane;
    int myrel = -1, s_l = 0, t_l = 0, tt_l = 0;
    if (e < ET) {
      const int* rec = (e < EN) ? (nedg + (size_t)e * 5) : (sedg + (size_t)(e - EN) * 5);
      s_l = rec[0]; t_l = rec[2]; tt_l = rec[3]; myrel = rec[4];
    }
    unsigned long long m = __ballot(myrel == r);
    while (m) {
      const int b = __builtin_ctzll(m);
      m &= m - 1;
      const int e_u = e0 + b;
      const int s = __shfl(s_l, b, 64);
      const int t = __shfl(t_l, b, 64);
      const int tt = __shfl(tt_l, b, 64);

      // intents = softmax(tgt @ W_intent[tt] + b_intent[tt])
      const float* tg = ent + (size_t)t * D;
      const float tg0 = tg[lane], tg1 = tg[lane + 64];
      float p[NI];
#pragma unroll
      for (int j = 0; j < NI; j++) {
        const float* w = &lWintT[(tt * NI + j) * D];
        p[j] = tg0 * w[lane] + tg1 * w[lane + 64];
      }
#pragma unroll
      for (int j = 0; j < NI; j++) p[j] = wave_sum(p[j]) + lbint[tt * NI + j];
      float mx = p[0];
#pragma unroll
      for (int j = 1; j < NI; j++) mx = fmaxf(mx, p[j]);
      float ssum = 0.f;
#pragma unroll
      for (int j = 0; j < NI; j++) { p[j] = __expf(p[j] - mx); ssum += p[j]; }
      const float inv = 1.f / ssum;

      // rel_w = softmax(intents @ W_ibn[tt] + b_ibn[tt]); iw = rel_w[r]
      float q[NR];
#pragma unroll
      for (int k = 0; k < NR; k++) q[k] = lbibn[tt * NR + k];
#pragma unroll
      for (int j = 0; j < NI; j++) {
        const float ij = p[j] * inv;
#pragma unroll
        for (int k = 0; k < NR; k++) q[k] += ij * lWibn[(tt * NI + j) * NR + k];
      }
      float mx9 = q[0];
#pragma unroll
      for (int k = 1; k < NR; k++) mx9 = fmaxf(mx9, q[k]);
      float s9 = 0.f;
#pragma unroll
      for (int k = 0; k < NR; k++) s9 += __expf(q[k] - mx9);
      const float iw = __expf(q[r] - mx9) / s9;

      // src_rel = selu(src @ W_rel[r] + b_rel[r]); score = iw * <src_rel, rel_e[r]>
      const float* sg = ent + (size_t)s * D;
      lsrc[wv][lane] = sg[lane];
      lsrc[wv][lane + 64] = sg[lane + 64];
      float acc = 0.f;
#pragma unroll 8
      for (int i = 0; i < D; i++) acc = fmaf(lsrc[wv][i], lWrel[i * DR + lane], acc);
      const float x = acc + lbrel[lane];
      const float sr = x > 0.f ? 1.0507009873554805f * x
                               : 1.7580993408473766f * expm1f(x);  // selu
      const float sc = wave_sum(sr * lrele[lane]) * iw;
      const float es = __expf(sc);
      if (lane == 0) {
        exps[e_u] = es;
        atomicAdd(&denom[t], es);
      }
    }
  }
}

// Kernel B: dist -> d_out, msg = dist * (src @ W_msg[r]) atomically into ent_out.
__global__ __launch_bounds__(256) void k_msg(
    const float* __restrict__ ent,
    const int* __restrict__ nedg, const int* __restrict__ sedg,
    const float* __restrict__ W_msg,
    const float* __restrict__ exps, const float* __restrict__ denom,
    float* __restrict__ dist_out, float* __restrict__ ent_out) {
  const int r = blockIdx.y;
  __shared__ float lW[D * D];  // 64 KB
  __shared__ float lsrc[4][D];
  const int tid = threadIdx.x;
  for (int i = tid; i < D * D; i += 256) lW[i] = W_msg[(size_t)r * D * D + i];
  __syncthreads();
  const int lane = tid & 63;
  const int wv = tid >> 6;
  const int base = blockIdx.x * CHUNK;
  for (int g = wv; g < CHUNK / 64; g += 4) {
    const int e0 = base + g * 64;
    const int e = e0 + lane;
    int myrel = -1, s_l = 0, t_l = 0;
    if (e < ET) {
      const int* rec = (e < EN) ? (nedg + (size_t)e * 5) : (sedg + (size_t)(e - EN) * 5);
      s_l = rec[0]; t_l = rec[2]; myrel = rec[4];
    }
    unsigned long long m = __ballot(myrel == r);
    while (m) {
      const int b = __builtin_ctzll(m);
      m &= m - 1;
      const int e_u = e0 + b;
      const int s = __shfl(s_l, b, 64);
      const int t = __shfl(t_l, b, 64);
      const float dist = exps[e_u] / denom[t];
      if (lane == 0) dist_out[e_u] = dist;
      const float* sg = ent + (size_t)s * D;
      lsrc[wv][lane] = sg[lane];
      lsrc[wv][lane + 64] = sg[lane + 64];
      float a0 = 0.f, a1 = 0.f;
#pragma unroll 8
      for (int i = 0; i < D; i++) {
        const float sv = lsrc[wv][i];
        const float2 w = *(const float2*)&lW[i * D + 2 * lane];
        a0 = fmaf(sv, w.x, a0);
        a1 = fmaf(sv, w.y, a1);
      }
      float* o = ent_out + (size_t)t * D + 2 * lane;
      atomicAdd(o, a0 * dist);
      atomicAdd(o + 1, a1 * dist);
    }
  }
}

extern "C" void kernel_launch(void* const* d_in, const int* in_sizes, int n_in,
                              void* d_out, int out_size, void* d_ws, size_t ws_size,
                              hipStream_t stream) {
  const int* nedg = (const int*)d_in[0];
  const int* ntypes = (const int*)d_in[1];
  const int* sedg = (const int*)d_in[2];
  const float* emb = (const float*)d_in[3];
  const float* def = (const float*)d_in[4];
  const float* rel_emb = (const float*)d_in[5];
  const float* W_rel = (const float*)d_in[6];
  const float* b_rel = (const float*)d_in[7];
  const float* W_msg = (const float*)d_in[8];
  const float* W_int = (const float*)d_in[9];
  const float* b_int = (const float*)d_in[10];
  const float* W_ibn = (const float*)d_in[11];
  const float* b_ibn = (const float*)d_in[12];
  float* out = (float*)d_out;

  float* entA = (float*)d_ws;                    // 12.8M floats
  float* entB = entA + (size_t)NE * D;           // 12.8M floats
  float* exps = entB + (size_t)NE * D;           // 254096
  float* denom = exps + ET;                      // 100000
  float* dist_base = out + (size_t)NE * D;       // 3 x 254096 in d_out

  k_init<<<dim3((NE * (D / 4) + 255) / 256), dim3(256), 0, stream>>>(entA, ntypes, def, emb);

  const int nchunk = (ET + CHUNK - 1) / CHUNK;  // 125
  const float* ent_in = entA;
  for (int l = 0; l < 3; l++) {
    float* ent_out = (l == 0) ? entB : (l == 1) ? entA : out;
    fill_zero<<<dim3((NE / 4 + 255) / 256), 256, 0, stream>>>((float4*)denom, NE / 4);
    fill_zero<<<dim3((NE * D / 4 + 255) / 256), 256, 0, stream>>>((float4*)ent_out, NE * D / 4);
    k_scores<<<dim3(nchunk, NR), 256, 0, stream>>>(ent_in, nedg, sedg, rel_emb, W_rel, b_rel,
                                                   W_int, b_int, W_ibn, b_ibn, exps, denom);
    k_msg<<<dim3(nchunk, NR), 256, 0, stream>>>(ent_in, nedg, sedg, W_msg, exps, denom,
                                                dist_base + (size_t)l * ET, ent_out);
    ent_in = ent_out;
  }
}

// Round 2
// 1526.387 us; speedup vs baseline: 2.1334x; 2.1334x over previous
//
#include <hip/hip_runtime.h>
#include <cstddef>
#include <cstdint>

#define NE 100000   // entities
#define EN 4096     // new edges
#define ET 254096   // total edges
#define D 128       // D_ENT
#define DR 64       // D_REL
#define NR 9        // relations
#define NT 3        // node types
#define NI 8        // intents
#define TE 256      // edges per tile
#define TILES_X 112

using frag  = __attribute__((ext_vector_type(8))) short;
using f32x4 = __attribute__((ext_vector_type(4))) float;

__device__ __forceinline__ ushort f2b(float x) {
  union { float f; uint32_t u; } v; v.f = x;
  uint32_t r = v.u + 0x7FFFu + ((v.u >> 16) & 1u);  // RNE
  return (ushort)(r >> 16);
}

// LDS tiles: row-major [rows][128] bf16, 16B chunks XOR-swizzled by (row&7).
__device__ __forceinline__ frag lds_rd(const ushort* b, int row, int k) {
  const int ch = ((k >> 3) ^ (row & 7));
  return *(const frag*)(b + row * D + (ch << 3));
}
__device__ __forceinline__ void lds_wr(ushort* b, int row, int ch, frag v) {
  *(frag*)(b + row * D + ((ch ^ (row & 7)) << 3)) = v;
}
__device__ __forceinline__ void lds_wr1(ushort* b, int row, int k, ushort v) {
  const int ch = (k >> 3) ^ (row & 7);
  b[row * D + (ch << 3) + (k & 7)] = v;
}

__global__ void fill_zero(float4* __restrict__ p, int n4) {
  int i = blockIdx.x * blockDim.x + threadIdx.x;
  if (i < n4) p[i] = make_float4(0.f, 0.f, 0.f, 0.f);
}

__global__ void k_init(ushort* __restrict__ entb, const int* __restrict__ ntypes,
                       const float* __restrict__ def, const float* __restrict__ emb) {
  int i = blockIdx.x * blockDim.x + threadIdx.x;  // one per 4 elems
  if (i >= NE * (D / 4)) return;
  int row = i >> 5, ch = i & 31;
  float4 v;
  if (row < EN) v = ((const float4*)(def + ntypes[row] * D))[ch];
  else v = ((const float4*)(emb + (size_t)(row - EN) * D))[ch];
  ushort4 h;
  h.x = f2b(v.x); h.y = f2b(v.y); h.z = f2b(v.z); h.w = f2b(v.w);
  ((ushort4*)entb)[i] = h;
}

__global__ void k_zero_cnt(int* cnt) { if (threadIdx.x < 16) cnt[threadIdx.x] = 0; }

__global__ void k_scatter(const int* __restrict__ nedg, const int* __restrict__ sedg,
                          int* __restrict__ cnt, int* __restrict__ bucket) {
  int e = blockIdx.x * blockDim.x + threadIdx.x;
  if (e >= ET) return;
  const int* p = (e < EN) ? nedg + (size_t)e * 5 : sedg + (size_t)(e - EN) * 5;
  int r = p[4];
  int pos = atomicAdd(&cnt[r], 1);
  bucket[(size_t)r * ET + pos] = e;
}

// Fused per-edge pass: intents -> iw -> scores -> exp_s (+denom), and
// unnormalized message accumulation acc[t] += exp_s * (src @ W_msg[r]).
__global__ __launch_bounds__(512) void k_pass1(
    const ushort* __restrict__ entb,
    const int* __restrict__ nedg, const int* __restrict__ sedg,
    const int* __restrict__ cnt, const int* __restrict__ bucket,
    const float* __restrict__ rel_emb,
    const float* __restrict__ W_rel, const float* __restrict__ b_rel,
    const float* __restrict__ W_msg,
    const float* __restrict__ W_int, const float* __restrict__ b_int,
    const float* __restrict__ W_ibn, const float* __restrict__ b_ibn,
    float* __restrict__ exps, float* __restrict__ denom,
    float* __restrict__ acc_out) {
  const int r = blockIdx.y;
  __shared__ ushort sA[TE * D];          // 64 KB: tgt then src tile (bf16, swizzled)
  __shared__ ushort sWm[D * D];          // 32 KB: W_msg^T [n][k]
  __shared__ ushort sWr[DR * D];         // 16 KB: W_rel^T [n][k]
  __shared__ ushort sWi[NT * 16 * D];    // 12 KB: W_int^T [tt*16+j][k], rows 8..15 zero
  __shared__ float sInt[TE][NI + 1];     // padded stride 9 (bank spread)
  __shared__ int sS[TE], sT[TE], sTT[TE], sE[TE];
  __shared__ float sIW[TE];
  __shared__ float sbrel[DR], srele[DR];
  __shared__ float sbint[NT * NI], sWibn[NT * NI * NR], sbibn[NT * NR];

  const int tid = threadIdx.x;
  const int lane = tid & 63;
  const int wv = tid >> 6;       // 0..7
  const int g = lane >> 4;       // 0..3
  const int c = lane & 15;       // 0..15

  // ---- load weights (once per block) ----
  for (int i = tid; i < D * DR; i += 512) {          // W_rel[r][k][n]
    int k = i / DR, n = i % DR;
    lds_wr1(sWr, n, k, f2b(W_rel[(size_t)r * D * DR + i]));
  }
  for (int i = tid; i < D * D; i += 512) {           // W_msg[r][k][n]
    int k = i >> 7, n = i & 127;
    lds_wr1(sWm, n, k, f2b(W_msg[(size_t)r * D * D + i]));
  }
  for (int i = tid; i < NT * D * NI; i += 512) {     // W_int[tt][k][j]
    int tt = i / (D * NI), rem = i % (D * NI), k = rem / NI, j = rem % NI;
    lds_wr1(sWi, tt * 16 + j, k, f2b(W_int[i]));
  }
  for (int i = tid; i < NT * 8 * D; i += 512) {      // zero pad rows
    int tt = i / (8 * D), rem = i % (8 * D), j = rem / D, k = rem % D;
    lds_wr1(sWi, tt * 16 + 8 + j, k, 0);
  }
  if (tid < DR) { sbrel[tid] = b_rel[r * DR + tid]; srele[tid] = rel_emb[r * DR + tid]; }
  for (int i = tid; i < NT * NI; i += 512) sbint[i] = b_int[i];
  for (int i = tid; i < NT * NI * NR; i += 512) sWibn[i] = W_ibn[i];
  for (int i = tid; i < NT * NR; i += 512) sbibn[i] = b_ibn[i];

  const int nr = cnt[r];
  const int ntiles = (nr + TE - 1) / TE;

  for (int tile = blockIdx.x; tile < ntiles; tile += gridDim.x) {
    const int e0 = tile * TE;
    const int ne = min(TE, nr - e0);
    __syncthreads();  // protect prev-tile LDS reads + first-tile weight writes

    // ---- edge meta ----
    int my_tt = 0;
    if (tid < TE) {
      int s = 0, t = 0, tt = 0, eg = 0;
      if (tid < ne) {
        eg = bucket[(size_t)r * ET + e0 + tid];
        const int* p = (eg < EN) ? nedg + (size_t)eg * 5 : sedg + (size_t)(eg - EN) * 5;
        s = p[0]; t = p[2]; tt = p[3];
      }
      sS[tid] = s; sT[tid] = t; sTT[tid] = tt; sE[tid] = eg;
      my_tt = tt;
    }
    __syncthreads();

    // ---- gather tgt -> sA ----
    {
      const int row = tid & 255, h = tid >> 8;
      const frag* rp = (const frag*)(entb + (size_t)sT[row] * D);
#pragma unroll
      for (int j = 0; j < 8; j++) lds_wr(sA, row, h * 8 + j, rp[h * 8 + j]);
    }
    __syncthreads();

    // ---- intent GEMM (3 types, N padded to 16) ----
    {
      f32x4 accI[2][NT];
#pragma unroll
      for (int mi = 0; mi < 2; mi++)
#pragma unroll
        for (int tt = 0; tt < NT; tt++) accI[mi][tt] = (f32x4){0.f, 0.f, 0.f, 0.f};
#pragma unroll
      for (int ks = 0; ks < 4; ks++) {
        const int k = ks * 32 + g * 8;
        frag a0 = lds_rd(sA, (wv * 2 + 0) * 16 + c, k);
        frag a1 = lds_rd(sA, (wv * 2 + 1) * 16 + c, k);
#pragma unroll
        for (int tt = 0; tt < NT; tt++) {
          frag b = lds_rd(sWi, tt * 16 + c, k);
          accI[0][tt] = __builtin_amdgcn_mfma_f32_16x16x32_bf16(a0, b, accI[0][tt], 0, 0, 0);
          accI[1][tt] = __builtin_amdgcn_mfma_f32_16x16x32_bf16(a1, b, accI[1][tt], 0, 0, 0);
        }
      }
      if (c < NI) {
#pragma unroll
        for (int mi = 0; mi < 2; mi++) {
          const int mb = (wv * 2 + mi) * 16 + g * 4;
#pragma unroll
          for (int tt = 0; tt < NT; tt++)
#pragma unroll
            for (int q = 0; q < 4; q++)
              if (sTT[mb + q] == tt) sInt[mb + q][c] = accI[mi][tt][q];
        }
      }
    }
    __syncthreads();

    // ---- gather src -> sA (reuse) + owner-thread softmax/iw ----
    {
      const int row = tid & 255, h = tid >> 8;
      const frag* rp = (const frag*)(entb + (size_t)sS[row] * D);
      frag tmp[8];
#pragma unroll
      for (int j = 0; j < 8; j++) tmp[j] = rp[h * 8 + j];  // loads in flight

      if (tid < ne) {
        const int tt = my_tt;
        float it[NI], mx = -1e30f;
#pragma unroll
        for (int j = 0; j < NI; j++) {
          it[j] = sInt[tid][j] + sbint[tt * NI + j];
          mx = fmaxf(mx, it[j]);
        }
        float ssum = 0.f;
#pragma unroll
        for (int j = 0; j < NI; j++) { it[j] = __expf(it[j] - mx); ssum += it[j]; }
        const float inv = 1.f / ssum;
        float qv[NR];
#pragma unroll
        for (int k = 0; k < NR; k++) qv[k] = sbibn[tt * NR + k];
#pragma unroll
        for (int j = 0; j < NI; j++) {
          const float ij = it[j] * inv;
#pragma unroll
          for (int k = 0; k < NR; k++) qv[k] = fmaf(ij, sWibn[(tt * NI + j) * NR + k], qv[k]);
        }
        float m9 = qv[0];
#pragma unroll
        for (int k = 1; k < NR; k++) m9 = fmaxf(m9, qv[k]);
        float s9 = 0.f;
#pragma unroll
        for (int k = 0; k < NR; k++) s9 += __expf(qv[k] - m9);
        sIW[tid] = __expf(qv[r] - m9) / s9;
      }
#pragma unroll
      for (int j = 0; j < 8; j++) lds_wr(sA, row, h * 8 + j, tmp[j]);
    }
    __syncthreads();

    // ---- main GEMMs: src @ W_rel (4 N-tiles) and src @ W_msg (8 N-tiles) ----
    f32x4 accR[2][4], accM[2][8];
#pragma unroll
    for (int mi = 0; mi < 2; mi++) {
#pragma unroll
      for (int nt = 0; nt < 4; nt++) accR[mi][nt] = (f32x4){0.f, 0.f, 0.f, 0.f};
#pragma unroll
      for (int nt = 0; nt < 8; nt++) accM[mi][nt] = (f32x4){0.f, 0.f, 0.f, 0.f};
    }
#pragma unroll
    for (int ks = 0; ks < 4; ks++) {
      const int k = ks * 32 + g * 8;
      frag a0 = lds_rd(sA, (wv * 2 + 0) * 16 + c, k);
      frag a1 = lds_rd(sA, (wv * 2 + 1) * 16 + c, k);
#pragma unroll
      for (int nt = 0; nt < 4; nt++) {
        frag b = lds_rd(sWr, nt * 16 + c, k);
        accR[0][nt] = __builtin_amdgcn_mfma_f32_16x16x32_bf16(a0, b, accR[0][nt], 0, 0, 0);
        accR[1][nt] = __builtin_amdgcn_mfma_f32_16x16x32_bf16(a1, b, accR[1][nt], 0, 0, 0);
      }
#pragma unroll
      for (int nt = 0; nt < 8; nt++) {
        frag b = lds_rd(sWm, nt * 16 + c, k);
        accM[0][nt] = __builtin_amdgcn_mfma_f32_16x16x32_bf16(a0, b, accM[0][nt], 0, 0, 0);
        accM[1][nt] = __builtin_amdgcn_mfma_f32_16x16x32_bf16(a1, b, accM[1][nt], 0, 0, 0);
      }
    }

    // ---- score epilogue: selu, dot rel_e, 16-lane reduce, exp, denom atomics ----
    float es[2][4];
    int tg[2][4];
#pragma unroll
    for (int mi = 0; mi < 2; mi++) {
      float v[4] = {0.f, 0.f, 0.f, 0.f};
#pragma unroll
      for (int nt = 0; nt < 4; nt++) {
        const int col = nt * 16 + c;
        const float br = sbrel[col], re = srele[col];
#pragma unroll
        for (int q = 0; q < 4; q++) {
          const float x = accR[mi][nt][q] + br;
          const float sl = x > 0.f ? 1.0507009873554805f * x
                                   : 1.7580993408473766f * expm1f(x);
          v[q] = fmaf(sl, re, v[q]);
        }
      }
#pragma unroll
      for (int off = 1; off < 16; off <<= 1)
#pragma unroll
        for (int q = 0; q < 4; q++) v[q] += __shfl_xor(v[q], off, 64);
      const int mb = (wv * 2 + mi) * 16 + g * 4;
#pragma unroll
      for (int q = 0; q < 4; q++) {
        const int m = mb + q;
        const float e_s = __expf(v[q] * sIW[m]);
        es[mi][q] = e_s;
        tg[mi][q] = sT[m];
        if (c == 0 && m < ne) {
          exps[sE[m]] = e_s;
          atomicAdd(&denom[tg[mi][q]], e_s);
        }
      }
    }

    // ---- message epilogue: acc[t] += es * (src @ W_msg) ----
#pragma unroll
    for (int mi = 0; mi < 2; mi++) {
      const int mb = (wv * 2 + mi) * 16 + g * 4;
#pragma unroll
      for (int nt = 0; nt < 8; nt++) {
#pragma unroll
        for (int q = 0; q < 4; q++) {
          const int m = mb + q;
          if (m < ne)
            atomicAdd(&acc_out[(size_t)tg[mi][q] * D + nt * 16 + c],
                      accM[mi][nt][q] * es[mi][q]);
        }
      }
    }
  }
}

// dist[e] = exps[e] / denom[t]
__global__ void k_dist(const int* __restrict__ nedg, const int* __restrict__ sedg,
                       const float* __restrict__ exps, const float* __restrict__ denom,
                       float* __restrict__ dout) {
  int e = blockIdx.x * blockDim.x + threadIdx.x;
  if (e >= ET) return;
  const int* p = (e < EN) ? nedg + (size_t)e * 5 : sedg + (size_t)(e - EN) * 5;
  const float d = denom[p[2]];
  dout[e] = (d != 0.f) ? exps[e] / d : 0.f;
}

// ent[t] = acc[t] / denom[t]; write bf16 (next layer input) and fp32 out on last layer.
__global__ void k_div(const float* __restrict__ acc, const float* __restrict__ denom,
                      ushort* __restrict__ entb, float* __restrict__ fout, int last) {
  int i = blockIdx.x * blockDim.x + threadIdx.x;  // per 4 elems
  if (i >= NE * (D / 4)) return;
  int row = i >> 5;
  const float d = denom[row];
  const float rec = (d != 0.f) ? 1.f / d : 0.f;
  float4 v = ((const float4*)acc)[i];
  v.x *= rec; v.y *= rec; v.z *= rec; v.w *= rec;
  ushort4 h;
  h.x = f2b(v.x); h.y = f2b(v.y); h.z = f2b(v.z); h.w = f2b(v.w);
  ((ushort4*)entb)[i] = h;
  if (last) ((float4*)fout)[i] = v;
}

extern "C" void kernel_launch(void* const* d_in, const int* in_sizes, int n_in,
                              void* d_out, int out_size, void* d_ws, size_t ws_size,
                              hipStream_t stream) {
  const int* nedg = (const int*)d_in[0];
  const int* ntypes = (const int*)d_in[1];
  const int* sedg = (const int*)d_in[2];
  const float* emb = (const float*)d_in[3];
  const float* def = (const float*)d_in[4];
  const float* rel_emb = (const float*)d_in[5];
  const float* W_rel = (const float*)d_in[6];
  const float* b_rel = (const float*)d_in[7];
  const float* W_msg = (const float*)d_in[8];
  const float* W_int = (const float*)d_in[9];
  const float* b_int = (const float*)d_in[10];
  const float* W_ibn = (const float*)d_in[11];
  const float* b_ibn = (const float*)d_in[12];
  float* out = (float*)d_out;

  char* w = (char*)d_ws;
  ushort* entb = (ushort*)w;                        // NE*128 bf16 (25.6 MB)
  float* acc = (float*)(w + (size_t)26 * 1024 * 1024);  // NE*128 f32 (51.2 MB)
  float* denom = acc + (size_t)NE * D;              // NE f32 (contiguous with acc)
  float* exps = denom + NE;                         // ET f32
  int* cnt = (int*)(exps + ET);                     // 16 ints
  int* bucket = cnt + 16;                           // 9*ET ints
  float* dist_base = out + (size_t)NE * D;

  k_init<<<dim3((NE * (D / 4) + 255) / 256), 256, 0, stream>>>(entb, ntypes, def, emb);
  k_zero_cnt<<<1, 64, 0, stream>>>(cnt);
  k_scatter<<<dim3((ET + 255) / 256), 256, 0, stream>>>(nedg, sedg, cnt, bucket);

  const int nz4 = (NE * D + NE) / 4;  // acc + denom jointly
  for (int l = 0; l < 3; l++) {
    fill_zero<<<dim3((nz4 + 255) / 256), 256, 0, stream>>>((float4*)acc, nz4);
    k_pass1<<<dim3(TILES_X, NR), 512, 0, stream>>>(
        entb, nedg, sedg, cnt, bucket, rel_emb, W_rel, b_rel, W_msg,
        W_int, b_int, W_ibn, b_ibn, exps, denom, acc);
    k_dist<<<dim3((ET + 255) / 256), 256, 0, stream>>>(nedg, sedg, exps, denom,
                                                       dist_base + (size_t)l * ET);
    k_div<<<dim3((NE * (D / 4) + 255) / 256), 256, 0, stream>>>(acc, denom, entb, out,
                                                                l == 2);
  }
}

// Round 3
// 647.051 us; speedup vs baseline: 5.0326x; 2.3590x over previous
//
#include <hip/hip_runtime.h>
#include <cstddef>
#include <cstdint>

#define NE 100000   // entities
#define EN 4096     // new edges
#define ET 254096   // total edges
#define D 128       // D_ENT
#define DR 64       // D_REL
#define NR 9        // relations
#define NT 3        // node types
#define NI 8        // intents
#define TE 256      // edges per tile
#define TILES_X 112

using frag  = __attribute__((ext_vector_type(8))) short;
using f32x4 = __attribute__((ext_vector_type(4))) float;

__device__ __forceinline__ ushort f2b(float x) {
  union { float f; uint32_t u; } v; v.f = x;
  uint32_t r = v.u + 0x7FFFu + ((v.u >> 16) & 1u);  // RNE
  return (ushort)(r >> 16);
}

// LDS tiles: row-major [rows][128] bf16, 16B chunks XOR-swizzled by (row&7).
__device__ __forceinline__ frag lds_rd(const ushort* b, int row, int k) {
  const int ch = ((k >> 3) ^ (row & 7));
  return *(const frag*)(b + row * D + (ch << 3));
}
__device__ __forceinline__ void lds_wr(ushort* b, int row, int ch, frag v) {
  *(frag*)(b + row * D + ((ch ^ (row & 7)) << 3)) = v;
}
__device__ __forceinline__ void lds_wr1(ushort* b, int row, int k, ushort v) {
  const int ch = (k >> 3) ^ (row & 7);
  b[row * D + (ch << 3) + (k & 7)] = v;
}

__global__ void fill_zero(float4* __restrict__ p, int n4) {
  int i = blockIdx.x * blockDim.x + threadIdx.x;
  if (i < n4) p[i] = make_float4(0.f, 0.f, 0.f, 0.f);
}

__global__ void k_init(ushort* __restrict__ entb, const int* __restrict__ ntypes,
                       const float* __restrict__ def, const float* __restrict__ emb) {
  int i = blockIdx.x * blockDim.x + threadIdx.x;  // one per 4 elems
  if (i >= NE * (D / 4)) return;
  int row = i >> 5, ch = i & 31;
  float4 v;
  if (row < EN) v = ((const float4*)(def + ntypes[row] * D))[ch];
  else v = ((const float4*)(emb + (size_t)(row - EN) * D))[ch];
  ushort4 h;
  h.x = f2b(v.x); h.y = f2b(v.y); h.z = f2b(v.z); h.w = f2b(v.w);
  ((ushort4*)entb)[i] = h;
}

__global__ void k_zero_cnt(int* cnt) { if (threadIdx.x < 48) cnt[threadIdx.x] = 0; }

// Phase 1: per-block LDS histogram -> <=9 global atomics per block.
__global__ __launch_bounds__(256) void k_hist(const int* __restrict__ nedg,
                                              const int* __restrict__ sedg,
                                              int* __restrict__ cnt) {
  __shared__ int h[NR];
  if (threadIdx.x < NR) h[threadIdx.x] = 0;
  __syncthreads();
  int e = blockIdx.x * 256 + threadIdx.x;
  if (e < ET) {
    const int* p = (e < EN) ? nedg + (size_t)e * 5 : sedg + (size_t)(e - EN) * 5;
    atomicAdd(&h[p[4]], 1);
  }
  __syncthreads();
  if (threadIdx.x < NR && h[threadIdx.x]) atomicAdd(&cnt[threadIdx.x], h[threadIdx.x]);
}

// Phase 2: exclusive prefix (9 values) -> base, head.
__global__ void k_prefix(const int* __restrict__ cnt, int* __restrict__ base,
                         int* __restrict__ head) {
  if (threadIdx.x == 0) {
    int acc = 0;
    for (int r = 0; r < NR; r++) { base[r] = acc; head[r] = acc; acc += cnt[r]; }
  }
}

// Phase 3: per-block range reservation + conflict-free writes (flat bucket).
__global__ __launch_bounds__(256) void k_scatter2(const int* __restrict__ nedg,
                                                  const int* __restrict__ sedg,
                                                  int* __restrict__ head,
                                                  int* __restrict__ bucket) {
  __shared__ int h[NR], bb[NR];
  if (threadIdx.x < NR) h[threadIdx.x] = 0;
  __syncthreads();
  int e = blockIdx.x * 256 + threadIdx.x;
  int r = -1, pos = 0;
  if (e < ET) {
    const int* p = (e < EN) ? nedg + (size_t)e * 5 : sedg + (size_t)(e - EN) * 5;
    r = p[4];
    pos = atomicAdd(&h[r], 1);
  }
  __syncthreads();
  if (threadIdx.x < NR)
    bb[threadIdx.x] = h[threadIdx.x] ? atomicAdd(&head[threadIdx.x], h[threadIdx.x]) : 0;
  __syncthreads();
  if (r >= 0) bucket[bb[r] + pos] = e;
}

// Fused per-edge pass: intents -> iw -> scores -> exp_s (+denom), and
// unnormalized message accumulation acc[t] += exp_s * (src @ W_msg[r]).
__global__ __launch_bounds__(512) void k_pass1(
    const ushort* __restrict__ entb,
    const int* __restrict__ nedg, const int* __restrict__ sedg,
    const int* __restrict__ cnt, const int* __restrict__ base_g,
    const int* __restrict__ bucket,
    const float* __restrict__ rel_emb,
    const float* __restrict__ W_rel, const float* __restrict__ b_rel,
    const float* __restrict__ W_msg,
    const float* __restrict__ W_int, const float* __restrict__ b_int,
    const float* __restrict__ W_ibn, const float* __restrict__ b_ibn,
    float* __restrict__ exps, float* __restrict__ denom,
    float* __restrict__ acc_out) {
  const int r = blockIdx.y;
  __shared__ ushort sA[TE * D];          // 64 KB: tgt then src tile (bf16, swizzled)
  __shared__ ushort sWm[D * D];          // 32 KB: W_msg^T [n][k]
  __shared__ ushort sWr[DR * D];         // 16 KB: W_rel^T [n][k]
  __shared__ ushort sWi[NT * 16 * D];    // 12 KB: W_int^T [tt*16+j][k], rows 8..15 zero
  __shared__ float sInt[TE][NI + 1];     // padded stride 9 (bank spread)
  __shared__ int sS[TE], sT[TE], sTT[TE], sE[TE];
  __shared__ float sIW[TE];
  __shared__ float sbrel[DR], srele[DR];
  __shared__ float sbint[NT * NI], sWibn[NT * NI * NR], sbibn[NT * NR];

  const int tid = threadIdx.x;
  const int lane = tid & 63;
  const int wv = tid >> 6;       // 0..7
  const int g = lane >> 4;       // 0..3
  const int c = lane & 15;       // 0..15

  // ---- load weights (once per block) ----
  for (int i = tid; i < D * DR; i += 512) {          // W_rel[r][k][n]
    int k = i / DR, n = i % DR;
    lds_wr1(sWr, n, k, f2b(W_rel[(size_t)r * D * DR + i]));
  }
  for (int i = tid; i < D * D; i += 512) {           // W_msg[r][k][n]
    int k = i >> 7, n = i & 127;
    lds_wr1(sWm, n, k, f2b(W_msg[(size_t)r * D * D + i]));
  }
  for (int i = tid; i < NT * D * NI; i += 512) {     // W_int[tt][k][j]
    int tt = i / (D * NI), rem = i % (D * NI), k = rem / NI, j = rem % NI;
    lds_wr1(sWi, tt * 16 + j, k, f2b(W_int[i]));
  }
  for (int i = tid; i < NT * 8 * D; i += 512) {      // zero pad rows
    int tt = i / (8 * D), rem = i % (8 * D), j = rem / D, k = rem % D;
    lds_wr1(sWi, tt * 16 + 8 + j, k, 0);
  }
  if (tid < DR) { sbrel[tid] = b_rel[r * DR + tid]; srele[tid] = rel_emb[r * DR + tid]; }
  for (int i = tid; i < NT * NI; i += 512) sbint[i] = b_int[i];
  for (int i = tid; i < NT * NI * NR; i += 512) sWibn[i] = W_ibn[i];
  for (int i = tid; i < NT * NR; i += 512) sbibn[i] = b_ibn[i];

  const int nr = cnt[r];
  const int bbase = base_g[r];
  const int ntiles = (nr + TE - 1) / TE;

  for (int tile = blockIdx.x; tile < ntiles; tile += gridDim.x) {
    const int e0 = tile * TE;
    const int ne = min(TE, nr - e0);
    __syncthreads();  // protect prev-tile LDS reads + first-tile weight writes

    // ---- edge meta ----
    int my_tt = 0;
    if (tid < TE) {
      int s = 0, t = 0, tt = 0, eg = 0;
      if (tid < ne) {
        eg = bucket[bbase + e0 + tid];
        const int* p = (eg < EN) ? nedg + (size_t)eg * 5 : sedg + (size_t)(eg - EN) * 5;
        s = p[0]; t = p[2]; tt = p[3];
      }
      sS[tid] = s; sT[tid] = t; sTT[tid] = tt; sE[tid] = eg;
      my_tt = tt;
    }
    __syncthreads();

    // ---- gather tgt -> sA ----
    {
      const int row = tid & 255, h = tid >> 8;
      const frag* rp = (const frag*)(entb + (size_t)sT[row] * D);
#pragma unroll
      for (int j = 0; j < 8; j++) lds_wr(sA, row, h * 8 + j, rp[h * 8 + j]);
    }
    __syncthreads();

    // ---- intent GEMM (3 types, N padded to 16) ----
    {
      f32x4 accI[2][NT];
#pragma unroll
      for (int mi = 0; mi < 2; mi++)
#pragma unroll
        for (int tt = 0; tt < NT; tt++) accI[mi][tt] = (f32x4){0.f, 0.f, 0.f, 0.f};
#pragma unroll
      for (int ks = 0; ks < 4; ks++) {
        const int k = ks * 32 + g * 8;
        frag a0 = lds_rd(sA, (wv * 2 + 0) * 16 + c, k);
        frag a1 = lds_rd(sA, (wv * 2 + 1) * 16 + c, k);
#pragma unroll
        for (int tt = 0; tt < NT; tt++) {
          frag b = lds_rd(sWi, tt * 16 + c, k);
          accI[0][tt] = __builtin_amdgcn_mfma_f32_16x16x32_bf16(a0, b, accI[0][tt], 0, 0, 0);
          accI[1][tt] = __builtin_amdgcn_mfma_f32_16x16x32_bf16(a1, b, accI[1][tt], 0, 0, 0);
        }
      }
      if (c < NI) {
#pragma unroll
        for (int mi = 0; mi < 2; mi++) {
          const int mb = (wv * 2 + mi) * 16 + g * 4;
#pragma unroll
          for (int tt = 0; tt < NT; tt++)
#pragma unroll
            for (int q = 0; q < 4; q++)
              if (sTT[mb + q] == tt) sInt[mb + q][c] = accI[mi][tt][q];
        }
      }
    }
    __syncthreads();

    // ---- gather src -> sA (reuse) + owner-thread softmax/iw ----
    {
      const int row = tid & 255, h = tid >> 8;
      const frag* rp = (const frag*)(entb + (size_t)sS[row] * D);
      frag tmp[8];
#pragma unroll
      for (int j = 0; j < 8; j++) tmp[j] = rp[h * 8 + j];  // loads in flight

      if (tid < ne) {
        const int tt = my_tt;
        float it[NI], mx = -1e30f;
#pragma unroll
        for (int j = 0; j < NI; j++) {
          it[j] = sInt[tid][j] + sbint[tt * NI + j];
          mx = fmaxf(mx, it[j]);
        }
        float ssum = 0.f;
#pragma unroll
        for (int j = 0; j < NI; j++) { it[j] = __expf(it[j] - mx); ssum += it[j]; }
        const float inv = 1.f / ssum;
        float qv[NR];
#pragma unroll
        for (int k = 0; k < NR; k++) qv[k] = sbibn[tt * NR + k];
#pragma unroll
        for (int j = 0; j < NI; j++) {
          const float ij = it[j] * inv;
#pragma unroll
          for (int k = 0; k < NR; k++) qv[k] = fmaf(ij, sWibn[(tt * NI + j) * NR + k], qv[k]);
        }
        float m9 = qv[0];
#pragma unroll
        for (int k = 1; k < NR; k++) m9 = fmaxf(m9, qv[k]);
        float s9 = 0.f;
#pragma unroll
        for (int k = 0; k < NR; k++) s9 += __expf(qv[k] - m9);
        sIW[tid] = __expf(qv[r] - m9) / s9;
      }
#pragma unroll
      for (int j = 0; j < 8; j++) lds_wr(sA, row, h * 8 + j, tmp[j]);
    }
    __syncthreads();

    // ---- main GEMMs: src @ W_rel (4 N-tiles) and src @ W_msg (8 N-tiles) ----
    f32x4 accR[2][4], accM[2][8];
#pragma unroll
    for (int mi = 0; mi < 2; mi++) {
#pragma unroll
      for (int nt = 0; nt < 4; nt++) accR[mi][nt] = (f32x4){0.f, 0.f, 0.f, 0.f};
#pragma unroll
      for (int nt = 0; nt < 8; nt++) accM[mi][nt] = (f32x4){0.f, 0.f, 0.f, 0.f};
    }
#pragma unroll
    for (int ks = 0; ks < 4; ks++) {
      const int k = ks * 32 + g * 8;
      frag a0 = lds_rd(sA, (wv * 2 + 0) * 16 + c, k);
      frag a1 = lds_rd(sA, (wv * 2 + 1) * 16 + c, k);
#pragma unroll
      for (int nt = 0; nt < 4; nt++) {
        frag b = lds_rd(sWr, nt * 16 + c, k);
        accR[0][nt] = __builtin_amdgcn_mfma_f32_16x16x32_bf16(a0, b, accR[0][nt], 0, 0, 0);
        accR[1][nt] = __builtin_amdgcn_mfma_f32_16x16x32_bf16(a1, b, accR[1][nt], 0, 0, 0);
      }
#pragma unroll
      for (int nt = 0; nt < 8; nt++) {
        frag b = lds_rd(sWm, nt * 16 + c, k);
        accM[0][nt] = __builtin_amdgcn_mfma_f32_16x16x32_bf16(a0, b, accM[0][nt], 0, 0, 0);
        accM[1][nt] = __builtin_amdgcn_mfma_f32_16x16x32_bf16(a1, b, accM[1][nt], 0, 0, 0);
      }
    }

    // ---- score epilogue: selu, dot rel_e, 16-lane reduce, exp, denom atomics ----
    float es[2][4];
    int tg[2][4];
#pragma unroll
    for (int mi = 0; mi < 2; mi++) {
      float v[4] = {0.f, 0.f, 0.f, 0.f};
#pragma unroll
      for (int nt = 0; nt < 4; nt++) {
        const int col = nt * 16 + c;
        const float br = sbrel[col], re = srele[col];
#pragma unroll
        for (int q = 0; q < 4; q++) {
          const float x = accR[mi][nt][q] + br;
          const float sl = x > 0.f ? 1.0507009873554805f * x
                                   : 1.7580993408473766f * expm1f(x);
          v[q] = fmaf(sl, re, v[q]);
        }
      }
#pragma unroll
      for (int off = 1; off < 16; off <<= 1)
#pragma unroll
        for (int q = 0; q < 4; q++) v[q] += __shfl_xor(v[q], off, 64);
      const int mb = (wv * 2 + mi) * 16 + g * 4;
#pragma unroll
      for (int q = 0; q < 4; q++) {
        const int m = mb + q;
        const float e_s = __expf(v[q] * sIW[m]);
        es[mi][q] = e_s;
        tg[mi][q] = sT[m];
        if (c == 0 && m < ne) {
          exps[sE[m]] = e_s;
          atomicAdd(&denom[tg[mi][q]], e_s);
        }
      }
    }

    // ---- message epilogue: acc[t] += es * (src @ W_msg) ----
#pragma unroll
    for (int mi = 0; mi < 2; mi++) {
      const int mb = (wv * 2 + mi) * 16 + g * 4;
#pragma unroll
      for (int nt = 0; nt < 8; nt++) {
#pragma unroll
        for (int q = 0; q < 4; q++) {
          const int m = mb + q;
          if (m < ne)
            atomicAdd(&acc_out[(size_t)tg[mi][q] * D + nt * 16 + c],
                      accM[mi][nt][q] * es[mi][q]);
        }
      }
    }
  }
}

// dist[e] = exps[e] / denom[t]
__global__ void k_dist(const int* __restrict__ nedg, const int* __restrict__ sedg,
                       const float* __restrict__ exps, const float* __restrict__ denom,
                       float* __restrict__ dout) {
  int e = blockIdx.x * blockDim.x + threadIdx.x;
  if (e >= ET) return;
  const int* p = (e < EN) ? nedg + (size_t)e * 5 : sedg + (size_t)(e - EN) * 5;
  const float d = denom[p[2]];
  dout[e] = (d != 0.f) ? exps[e] / d : 0.f;
}

// ent[t] = acc[t] / denom[t]; write bf16 (next layer input) and fp32 out on last layer.
__global__ void k_div(const float* __restrict__ acc, const float* __restrict__ denom,
                      ushort* __restrict__ entb, float* __restrict__ fout, int last) {
  int i = blockIdx.x * blockDim.x + threadIdx.x;  // per 4 elems
  if (i >= NE * (D / 4)) return;
  int row = i >> 5;
  const float d = denom[row];
  const float rec = (d != 0.f) ? 1.f / d : 0.f;
  float4 v = ((const float4*)acc)[i];
  v.x *= rec; v.y *= rec; v.z *= rec; v.w *= rec;
  ushort4 h;
  h.x = f2b(v.x); h.y = f2b(v.y); h.z = f2b(v.z); h.w = f2b(v.w);
  ((ushort4*)entb)[i] = h;
  if (last) ((float4*)fout)[i] = v;
}

extern "C" void kernel_launch(void* const* d_in, const int* in_sizes, int n_in,
                              void* d_out, int out_size, void* d_ws, size_t ws_size,
                              hipStream_t stream) {
  const int* nedg = (const int*)d_in[0];
  const int* ntypes = (const int*)d_in[1];
  const int* sedg = (const int*)d_in[2];
  const float* emb = (const float*)d_in[3];
  const float* def = (const float*)d_in[4];
  const float* rel_emb = (const float*)d_in[5];
  const float* W_rel = (const float*)d_in[6];
  const float* b_rel = (const float*)d_in[7];
  const float* W_msg = (const float*)d_in[8];
  const float* W_int = (const float*)d_in[9];
  const float* b_int = (const float*)d_in[10];
  const float* W_ibn = (const float*)d_in[11];
  const float* b_ibn = (const float*)d_in[12];
  float* out = (float*)d_out;

  char* w = (char*)d_ws;
  ushort* entb = (ushort*)w;                        // NE*128 bf16 (25.6 MB)
  float* acc = (float*)(w + (size_t)26 * 1024 * 1024);  // NE*128 f32 (51.2 MB)
  float* denom = acc + (size_t)NE * D;              // NE f32 (contiguous with acc)
  float* exps = denom + NE;                         // ET f32
  int* cnt = (int*)(exps + ET);                     // 16 ints
  int* base_g = cnt + 16;                           // 16 ints
  int* head = base_g + 16;                          // 16 ints
  int* bucket = head + 16;                          // ET ints (flat)
  float* dist_base = out + (size_t)NE * D;

  const int eblocks = (ET + 255) / 256;
  k_init<<<dim3((NE * (D / 4) + 255) / 256), 256, 0, stream>>>(entb, ntypes, def, emb);
  k_zero_cnt<<<1, 64, 0, stream>>>(cnt);
  k_hist<<<dim3(eblocks), 256, 0, stream>>>(nedg, sedg, cnt);
  k_prefix<<<1, 64, 0, stream>>>(cnt, base_g, head);
  k_scatter2<<<dim3(eblocks), 256, 0, stream>>>(nedg, sedg, head, bucket);

  const int nz4 = (NE * D + NE) / 4;  // acc + denom jointly
  for (int l = 0; l < 3; l++) {
    fill_zero<<<dim3((nz4 + 255) / 256), 256, 0, stream>>>((float4*)acc, nz4);
    k_pass1<<<dim3(TILES_X, NR), 512, 0, stream>>>(
        entb, nedg, sedg, cnt, base_g, bucket, rel_emb, W_rel, b_rel, W_msg,
        W_int, b_int, W_ibn, b_ibn, exps, denom, acc);
    k_dist<<<dim3((ET + 255) / 256), 256, 0, stream>>>(nedg, sedg, exps, denom,
                                                       dist_base + (size_t)l * ET);
    k_div<<<dim3((NE * (D / 4) + 255) / 256), 256, 0, stream>>>(acc, denom, entb, out,
                                                                l == 2);
  }
}

// Round 4
// 586.697 us; speedup vs baseline: 5.5503x; 1.1029x over previous
//
#include <hip/hip_runtime.h>
#include <cstddef>
#include <cstdint>

#define NE 100000   // entities
#define EN 4096     // new edges
#define ET 254096   // total edges
#define D 128       // D_ENT
#define DR 64       // D_REL
#define NR 9        // relations
#define NT 3        // node types
#define NI 8        // intents
#define TE 256      // edges per tile
#define TILES_X 28  // blocks per relation (252 total ~ 1/CU)

using frag  = __attribute__((ext_vector_type(8))) short;
using f32x4 = __attribute__((ext_vector_type(4))) float;

__device__ __forceinline__ ushort f2b(float x) {
  union { float f; uint32_t u; } v; v.f = x;
  uint32_t r = v.u + 0x7FFFu + ((v.u >> 16) & 1u);  // RNE
  return (ushort)(r >> 16);
}

// LDS tiles: row-major [rows][128] bf16, 16B chunks XOR-swizzled by (row&7).
__device__ __forceinline__ frag lds_rd(const ushort* b, int row, int k) {
  const int ch = ((k >> 3) ^ (row & 7));
  return *(const frag*)(b + row * D + (ch << 3));
}
__device__ __forceinline__ void lds_wr(ushort* b, int row, int ch, frag v) {
  *(frag*)(b + row * D + ((ch ^ (row & 7)) << 3)) = v;
}
__device__ __forceinline__ void lds_wr2(ushort* b, int row, int k, uint32_t v) {
  const int ch = (k >> 3) ^ (row & 7);               // k even, pair (k,k+1)
  *(uint32_t*)(b + row * D + (ch << 3) + (k & 7)) = v;
}

__global__ void fill_zero(float4* __restrict__ p, int n4) {
  int i = blockIdx.x * blockDim.x + threadIdx.x;
  if (i < n4) p[i] = make_float4(0.f, 0.f, 0.f, 0.f);
}

__global__ void k_init(ushort* __restrict__ entb, const int* __restrict__ ntypes,
                       const float* __restrict__ def, const float* __restrict__ emb) {
  int i = blockIdx.x * blockDim.x + threadIdx.x;  // one per 4 elems
  if (i >= NE * (D / 4)) return;
  int row = i >> 5, ch = i & 31;
  float4 v;
  if (row < EN) v = ((const float4*)(def + ntypes[row] * D))[ch];
  else v = ((const float4*)(emb + (size_t)(row - EN) * D))[ch];
  ushort4 h;
  h.x = f2b(v.x); h.y = f2b(v.y); h.z = f2b(v.z); h.w = f2b(v.w);
  ((ushort4*)entb)[i] = h;
}

__global__ void k_zero_cnt(int* cnt) { if (threadIdx.x < 48) cnt[threadIdx.x] = 0; }

// Phase 1: per-block LDS histogram -> <=9 global atomics per block.
__global__ __launch_bounds__(256) void k_hist(const int* __restrict__ nedg,
                                              const int* __restrict__ sedg,
                                              int* __restrict__ cnt) {
  __shared__ int h[NR];
  if (threadIdx.x < NR) h[threadIdx.x] = 0;
  __syncthreads();
  int e = blockIdx.x * 256 + threadIdx.x;
  if (e < ET) {
    const int* p = (e < EN) ? nedg + (size_t)e * 5 : sedg + (size_t)(e - EN) * 5;
    atomicAdd(&h[p[4]], 1);
  }
  __syncthreads();
  if (threadIdx.x < NR && h[threadIdx.x]) atomicAdd(&cnt[threadIdx.x], h[threadIdx.x]);
}

// Phase 2: exclusive prefix (9 values) -> base, head.
__global__ void k_prefix(const int* __restrict__ cnt, int* __restrict__ base,
                         int* __restrict__ head) {
  if (threadIdx.x == 0) {
    int acc = 0;
    for (int r = 0; r < NR; r++) { base[r] = acc; head[r] = acc; acc += cnt[r]; }
  }
}

// Phase 3: per-block range reservation + conflict-free writes (flat bucket).
__global__ __launch_bounds__(256) void k_scatter2(const int* __restrict__ nedg,
                                                  const int* __restrict__ sedg,
                                                  int* __restrict__ head,
                                                  int* __restrict__ bucket) {
  __shared__ int h[NR], bb[NR];
  if (threadIdx.x < NR) h[threadIdx.x] = 0;
  __syncthreads();
  int e = blockIdx.x * 256 + threadIdx.x;
  int r = -1, pos = 0;
  if (e < ET) {
    const int* p = (e < EN) ? nedg + (size_t)e * 5 : sedg + (size_t)(e - EN) * 5;
    r = p[4];
    pos = atomicAdd(&h[r], 1);
  }
  __syncthreads();
  if (threadIdx.x < NR)
    bb[threadIdx.x] = h[threadIdx.x] ? atomicAdd(&head[threadIdx.x], h[threadIdx.x]) : 0;
  __syncthreads();
  if (r >= 0) bucket[bb[r] + pos] = e;
}

// Fused per-edge pass: intents -> iw -> scores -> exp_s (+denom), and
// unnormalized message accumulation acc[t] += exp_s * (src @ W_msg[r]).
// 1024 threads = 16 waves; each wave owns one 16-row M-tile of the 256-edge tile.
__global__ __launch_bounds__(1024) void k_pass1(
    const ushort* __restrict__ entb,
    const int* __restrict__ nedg, const int* __restrict__ sedg,
    const int* __restrict__ cnt, const int* __restrict__ base_g,
    const int* __restrict__ bucket,
    const float* __restrict__ rel_emb,
    const float* __restrict__ W_rel, const float* __restrict__ b_rel,
    const float* __restrict__ W_msg,
    const float* __restrict__ W_int, const float* __restrict__ b_int,
    const float* __restrict__ W_ibn, const float* __restrict__ b_ibn,
    float* __restrict__ exps, float* __restrict__ denom,
    float* __restrict__ acc_out) {
  const int r = blockIdx.y;
  __shared__ ushort sA[TE * D];          // 64 KB: tgt then src tile (bf16, swizzled)
  __shared__ ushort sWm[D * D];          // 32 KB: W_msg^T [n][k]
  __shared__ ushort sWr[DR * D];         // 16 KB: W_rel^T [n][k]
  __shared__ ushort sWi[NT * 16 * D];    // 12 KB: W_int^T [tt*16+j][k], rows 8..15 zero
  __shared__ float sInt[TE][NI + 1];     // padded stride 9
  __shared__ int sS[TE], sT[TE], sTT[TE], sE[TE];
  __shared__ float sIW[TE];
  __shared__ float sbrel[DR], srele[DR];
  __shared__ float sbint[NT * NI], sWibn[NT * NI * NR], sbibn[NT * NR];

  const int tid = threadIdx.x;
  const int lane = tid & 63;
  const int wv = tid >> 6;       // 0..15
  const int g = lane >> 4;       // 0..3
  const int c = lane & 15;       // 0..15

  // ---- load weights (once per block), bf16 pairs packed as u32 ----
  const float* Wr = W_rel + (size_t)r * D * DR;
  for (int i = tid; i < (D / 2) * DR; i += 1024) {   // [k][n] -> sWr[n][k,k+1]
    int k2 = i / DR, n = i % DR;
    float a = Wr[(2 * k2) * DR + n], b = Wr[(2 * k2 + 1) * DR + n];
    lds_wr2(sWr, n, 2 * k2, (uint32_t)f2b(a) | ((uint32_t)f2b(b) << 16));
  }
  const float* Wm = W_msg + (size_t)r * D * D;
  for (int i = tid; i < (D / 2) * D; i += 1024) {    // [k][n] -> sWm[n][k,k+1]
    int k2 = i >> 7, n = i & 127;
    float a = Wm[(2 * k2) * D + n], b = Wm[(2 * k2 + 1) * D + n];
    lds_wr2(sWm, n, 2 * k2, (uint32_t)f2b(a) | ((uint32_t)f2b(b) << 16));
  }
  for (int i = tid; i < NT * NI * (D / 2); i += 1024) {  // [tt][k][j] -> sWi[tt*16+j][k]
    int tt = i / (NI * D / 2), rem = i % (NI * D / 2), j = rem / (D / 2), k2 = rem % (D / 2);
    const float* Wi = W_int + (size_t)tt * D * NI;
    float a = Wi[(2 * k2) * NI + j], b = Wi[(2 * k2 + 1) * NI + j];
    lds_wr2(sWi, tt * 16 + j, 2 * k2, (uint32_t)f2b(a) | ((uint32_t)f2b(b) << 16));
  }
  for (int i = tid; i < NT * 8 * (D / 2); i += 1024) {   // zero pad rows 8..15
    int tt = i / (8 * D / 2), rem = i % (8 * D / 2), j = rem / (D / 2), k2 = rem % (D / 2);
    lds_wr2(sWi, tt * 16 + 8 + j, 2 * k2, 0u);
  }
  if (tid < DR) { sbrel[tid] = b_rel[r * DR + tid]; srele[tid] = rel_emb[r * DR + tid]; }
  for (int i = tid; i < NT * NI; i += 1024) sbint[i] = b_int[i];
  for (int i = tid; i < NT * NI * NR; i += 1024) sWibn[i] = W_ibn[i];
  for (int i = tid; i < NT * NR; i += 1024) sbibn[i] = b_ibn[i];

  const int nr = cnt[r];
  const int bbase = base_g[r];
  const int ntiles = (nr + TE - 1) / TE;

  for (int tile = blockIdx.x; tile < ntiles; tile += gridDim.x) {
    const int e0 = tile * TE;
    const int ne = min(TE, nr - e0);
    __syncthreads();  // protect prev-tile LDS reads + first-tile weight writes

    // ---- edge meta ----
    int my_tt = 0;
    if (tid < TE) {
      int s = 0, t = 0, tt = 0, eg = 0;
      if (tid < ne) {
        eg = bucket[bbase + e0 + tid];
        const int* p = (eg < EN) ? nedg + (size_t)eg * 5 : sedg + (size_t)(eg - EN) * 5;
        s = p[0]; t = p[2]; tt = p[3];
      }
      sS[tid] = s; sT[tid] = t; sTT[tid] = tt; sE[tid] = eg;
      my_tt = tt;
    }
    __syncthreads();

    // ---- gather tgt -> sA (4 threads/row, 4x16B each) ----
    {
      const int row = tid & 255, h = tid >> 8;
      const frag* rp = (const frag*)(entb + (size_t)sT[row] * D);
#pragma unroll
      for (int j = 0; j < 4; j++) lds_wr(sA, row, h * 4 + j, rp[h * 4 + j]);
    }
    __syncthreads();

    // ---- intent GEMM (3 types, N padded to 16) ----
    {
      f32x4 accI[NT];
#pragma unroll
      for (int tt = 0; tt < NT; tt++) accI[tt] = (f32x4){0.f, 0.f, 0.f, 0.f};
#pragma unroll
      for (int ks = 0; ks < 4; ks++) {
        const int k = ks * 32 + g * 8;
        frag a0 = lds_rd(sA, wv * 16 + c, k);
#pragma unroll
        for (int tt = 0; tt < NT; tt++) {
          frag b = lds_rd(sWi, tt * 16 + c, k);
          accI[tt] = __builtin_amdgcn_mfma_f32_16x16x32_bf16(a0, b, accI[tt], 0, 0, 0);
        }
      }
      if (c < NI) {
        const int mb = wv * 16 + g * 4;
#pragma unroll
        for (int tt = 0; tt < NT; tt++)
#pragma unroll
          for (int q = 0; q < 4; q++)
            if (sTT[mb + q] == tt) sInt[mb + q][c] = accI[tt][q];
      }
    }
    __syncthreads();

    // ---- gather src -> sA (reuse) + owner-thread softmax/iw ----
    {
      const int row = tid & 255, h = tid >> 8;
      const frag* rp = (const frag*)(entb + (size_t)sS[row] * D);
      frag tmp[4];
#pragma unroll
      for (int j = 0; j < 4; j++) tmp[j] = rp[h * 4 + j];  // loads in flight

      if (tid < ne) {
        const int tt = my_tt;
        float it[NI], mx = -1e30f;
#pragma unroll
        for (int j = 0; j < NI; j++) {
          it[j] = sInt[tid][j] + sbint[tt * NI + j];
          mx = fmaxf(mx, it[j]);
        }
        float ssum = 0.f;
#pragma unroll
        for (int j = 0; j < NI; j++) { it[j] = __expf(it[j] - mx); ssum += it[j]; }
        const float inv = 1.f / ssum;
        float qv[NR];
#pragma unroll
        for (int k = 0; k < NR; k++) qv[k] = sbibn[tt * NR + k];
#pragma unroll
        for (int j = 0; j < NI; j++) {
          const float ij = it[j] * inv;
#pragma unroll
          for (int k = 0; k < NR; k++) qv[k] = fmaf(ij, sWibn[(tt * NI + j) * NR + k], qv[k]);
        }
        float m9 = qv[0];
#pragma unroll
        for (int k = 1; k < NR; k++) m9 = fmaxf(m9, qv[k]);
        float s9 = 0.f;
#pragma unroll
        for (int k = 0; k < NR; k++) s9 += __expf(qv[k] - m9);
        sIW[tid] = __expf(qv[r] - m9) / s9;
      }
#pragma unroll
      for (int j = 0; j < 4; j++) lds_wr(sA, row, h * 4 + j, tmp[j]);
    }
    __syncthreads();

    // ---- main GEMMs: src @ W_rel (4 N-tiles) and src @ W_msg (8 N-tiles) ----
    f32x4 accR[4], accM[8];
#pragma unroll
    for (int nt = 0; nt < 4; nt++) accR[nt] = (f32x4){0.f, 0.f, 0.f, 0.f};
#pragma unroll
    for (int nt = 0; nt < 8; nt++) accM[nt] = (f32x4){0.f, 0.f, 0.f, 0.f};
#pragma unroll
    for (int ks = 0; ks < 4; ks++) {
      const int k = ks * 32 + g * 8;
      frag a0 = lds_rd(sA, wv * 16 + c, k);
#pragma unroll
      for (int nt = 0; nt < 4; nt++) {
        frag b = lds_rd(sWr, nt * 16 + c, k);
        accR[nt] = __builtin_amdgcn_mfma_f32_16x16x32_bf16(a0, b, accR[nt], 0, 0, 0);
      }
#pragma unroll
      for (int nt = 0; nt < 8; nt++) {
        frag b = lds_rd(sWm, nt * 16 + c, k);
        accM[nt] = __builtin_amdgcn_mfma_f32_16x16x32_bf16(a0, b, accM[nt], 0, 0, 0);
      }
    }

    // ---- score epilogue: selu, dot rel_e, 16-lane reduce, exp, denom atomics ----
    float es[4];
    int tg[4];
    {
      float v[4] = {0.f, 0.f, 0.f, 0.f};
#pragma unroll
      for (int nt = 0; nt < 4; nt++) {
        const int col = nt * 16 + c;
        const float br = sbrel[col], re = srele[col];
#pragma unroll
        for (int q = 0; q < 4; q++) {
          const float x = accR[nt][q] + br;
          const float sl = x > 0.f ? 1.0507009873554805f * x
                                   : 1.7580993408473766f * expm1f(x);
          v[q] = fmaf(sl, re, v[q]);
        }
      }
#pragma unroll
      for (int off = 1; off < 16; off <<= 1)
#pragma unroll
        for (int q = 0; q < 4; q++) v[q] += __shfl_xor(v[q], off, 64);
      const int mb = wv * 16 + g * 4;
#pragma unroll
      for (int q = 0; q < 4; q++) {
        const int m = mb + q;
        const float e_s = __expf(v[q] * sIW[m]);
        es[q] = e_s;
        tg[q] = sT[m];
        if (c == 0 && m < ne) {
          exps[sE[m]] = e_s;
          atomicAdd(&denom[tg[q]], e_s);
        }
      }
    }

    // ---- message epilogue: acc[t] += es * (src @ W_msg) ----
    {
      const int mb = wv * 16 + g * 4;
#pragma unroll
      for (int nt = 0; nt < 8; nt++) {
#pragma unroll
        for (int q = 0; q < 4; q++) {
          if (mb + q < ne)
            atomicAdd(&acc_out[(size_t)tg[q] * D + nt * 16 + c], accM[nt][q] * es[q]);
        }
      }
    }
  }
}

// dist[e] = exps[e] / denom[t]
__global__ void k_dist(const int* __restrict__ nedg, const int* __restrict__ sedg,
                       const float* __restrict__ exps, const float* __restrict__ denom,
                       float* __restrict__ dout) {
  int e = blockIdx.x * blockDim.x + threadIdx.x;
  if (e >= ET) return;
  const int* p = (e < EN) ? nedg + (size_t)e * 5 : sedg + (size_t)(e - EN) * 5;
  const float d = denom[p[2]];
  dout[e] = (d != 0.f) ? exps[e] / d : 0.f;
}

// ent[t] = acc[t] / denom[t]; write bf16 (next layer input), fp32 out on last layer,
// and re-zero acc for the next layer (zacc) to skip a separate fill pass.
__global__ void k_div(const float* __restrict__ acc, const float* __restrict__ denom,
                      ushort* __restrict__ entb, float* __restrict__ fout, int last,
                      float* __restrict__ acc_z) {
  int i = blockIdx.x * blockDim.x + threadIdx.x;  // per 4 elems
  if (i >= NE * (D / 4)) return;
  int row = i >> 5;
  const float d = denom[row];
  const float rec = (d != 0.f) ? 1.f / d : 0.f;
  float4 v = ((const float4*)acc)[i];
  v.x *= rec; v.y *= rec; v.z *= rec; v.w *= rec;
  if (last) {
    ((float4*)fout)[i] = v;
  } else {
    ushort4 h;
    h.x = f2b(v.x); h.y = f2b(v.y); h.z = f2b(v.z); h.w = f2b(v.w);
    ((ushort4*)entb)[i] = h;
    ((float4*)acc_z)[i] = make_float4(0.f, 0.f, 0.f, 0.f);
  }
}

extern "C" void kernel_launch(void* const* d_in, const int* in_sizes, int n_in,
                              void* d_out, int out_size, void* d_ws, size_t ws_size,
                              hipStream_t stream) {
  const int* nedg = (const int*)d_in[0];
  const int* ntypes = (const int*)d_in[1];
  const int* sedg = (const int*)d_in[2];
  const float* emb = (const float*)d_in[3];
  const float* def = (const float*)d_in[4];
  const float* rel_emb = (const float*)d_in[5];
  const float* W_rel = (const float*)d_in[6];
  const float* b_rel = (const float*)d_in[7];
  const float* W_msg = (const float*)d_in[8];
  const float* W_int = (const float*)d_in[9];
  const float* b_int = (const float*)d_in[10];
  const float* W_ibn = (const float*)d_in[11];
  const float* b_ibn = (const float*)d_in[12];
  float* out = (float*)d_out;

  char* w = (char*)d_ws;
  ushort* entb = (ushort*)w;                        // NE*128 bf16 (25.6 MB)
  float* acc = (float*)(w + (size_t)26 * 1024 * 1024);  // NE*128 f32 (51.2 MB)
  float* denom = acc + (size_t)NE * D;              // NE f32
  float* exps = denom + NE;                         // ET f32
  int* cnt = (int*)(exps + ET);                     // 16 ints
  int* base_g = cnt + 16;                           // 16 ints
  int* head = base_g + 16;                          // 16 ints
  int* bucket = head + 16;                          // ET ints (flat)
  float* dist_base = out + (size_t)NE * D;

  const int eblocks = (ET + 255) / 256;
  k_init<<<dim3((NE * (D / 4) + 255) / 256), 256, 0, stream>>>(entb, ntypes, def, emb);
  k_zero_cnt<<<1, 64, 0, stream>>>(cnt);
  k_hist<<<dim3(eblocks), 256, 0, stream>>>(nedg, sedg, cnt);
  k_prefix<<<1, 64, 0, stream>>>(cnt, base_g, head);
  k_scatter2<<<dim3(eblocks), 256, 0, stream>>>(nedg, sedg, head, bucket);

  // zero acc + denom once (covers layer 0); later layers re-zero in k_div / tiny fill.
  const int nz4 = (NE * D + NE) / 4;
  fill_zero<<<dim3((nz4 + 255) / 256), 256, 0, stream>>>((float4*)acc, nz4);

  for (int l = 0; l < 3; l++) {
    k_pass1<<<dim3(TILES_X, NR), 1024, 0, stream>>>(
        entb, nedg, sedg, cnt, base_g, bucket, rel_emb, W_rel, b_rel, W_msg,
        W_int, b_int, W_ibn, b_ibn, exps, denom, acc);
    k_dist<<<dim3((ET + 255) / 256), 256, 0, stream>>>(nedg, sedg, exps, denom,
                                                       dist_base + (size_t)l * ET);
    k_div<<<dim3((NE * (D / 4) + 255) / 256), 256, 0, stream>>>(acc, denom, entb, out,
                                                                l == 2, acc);
    if (l < 2)  // denom for next layer
      fill_zero<<<dim3((NE / 4 + 255) / 256), 256, 0, stream>>>((float4*)denom, NE / 4);
  }
}

// Round 5
// 547.136 us; speedup vs baseline: 5.9517x; 1.0723x over previous
//
#include <hip/hip_runtime.h>
#include <cstddef>
#include <cstdint>

#define NE 100000   // entities
#define EN 4096     // new edges
#define ET 254096   // total edges
#define D 128       // D_ENT
#define DR 64       // D_REL
#define NR 9        // relations
#define NT 3        // node types
#define NI 8        // intents
#define TE 256      // edges per tile
#define TILES_X 28  // blocks per relation (252 total ~ 1/CU)

using frag  = __attribute__((ext_vector_type(8))) short;
using f32x4 = __attribute__((ext_vector_type(4))) float;

__device__ __forceinline__ ushort f2b(float x) {
  union { float f; uint32_t u; } v; v.f = x;
  uint32_t r = v.u + 0x7FFFu + ((v.u >> 16) & 1u);  // RNE
  return (ushort)(r >> 16);
}

// LDS tiles: row-major [rows][128] bf16, 16B chunks XOR-swizzled by (row&7).
__device__ __forceinline__ frag lds_rd(const ushort* b, int row, int k) {
  const int ch = ((k >> 3) ^ (row & 7));
  return *(const frag*)(b + row * D + (ch << 3));
}
__device__ __forceinline__ void lds_wr(ushort* b, int row, int ch, frag v) {
  *(frag*)(b + row * D + ((ch ^ (row & 7)) << 3)) = v;
}
__device__ __forceinline__ void lds_wr2(ushort* b, int row, int k, uint32_t v) {
  const int ch = (k >> 3) ^ (row & 7);               // k even, pair (k,k+1)
  *(uint32_t*)(b + row * D + (ch << 3) + (k & 7)) = v;
}

__global__ void fill_zero(float4* __restrict__ p, int n4) {
  int i = blockIdx.x * blockDim.x + threadIdx.x;
  if (i < n4) p[i] = make_float4(0.f, 0.f, 0.f, 0.f);
}

__global__ void k_init(ushort* __restrict__ entb, const int* __restrict__ ntypes,
                       const float* __restrict__ def, const float* __restrict__ emb) {
  int i = blockIdx.x * blockDim.x + threadIdx.x;  // one per 4 elems
  if (i >= NE * (D / 4)) return;
  int row = i >> 5, ch = i & 31;
  float4 v;
  if (row < EN) v = ((const float4*)(def + ntypes[row] * D))[ch];
  else v = ((const float4*)(emb + (size_t)(row - EN) * D))[ch];
  ushort4 h;
  h.x = f2b(v.x); h.y = f2b(v.y); h.z = f2b(v.z); h.w = f2b(v.w);
  ((ushort4*)entb)[i] = h;
}

__global__ void k_zero_cnt(int* cnt) { if (threadIdx.x < 48) cnt[threadIdx.x] = 0; }

// ---------- relation counting sort ----------
__global__ __launch_bounds__(256) void k_hist(const int* __restrict__ nedg,
                                              const int* __restrict__ sedg,
                                              int* __restrict__ cnt) {
  __shared__ int h[NR];
  if (threadIdx.x < NR) h[threadIdx.x] = 0;
  __syncthreads();
  int e = blockIdx.x * 256 + threadIdx.x;
  if (e < ET) {
    const int* p = (e < EN) ? nedg + (size_t)e * 5 : sedg + (size_t)(e - EN) * 5;
    atomicAdd(&h[p[4]], 1);
  }
  __syncthreads();
  if (threadIdx.x < NR && h[threadIdx.x]) atomicAdd(&cnt[threadIdx.x], h[threadIdx.x]);
}

__global__ void k_prefix(const int* __restrict__ cnt, int* __restrict__ base,
                         int* __restrict__ head) {
  if (threadIdx.x == 0) {
    int acc = 0;
    for (int r = 0; r < NR; r++) { base[r] = acc; head[r] = acc; acc += cnt[r]; }
  }
}

__global__ __launch_bounds__(256) void k_scatter2(const int* __restrict__ nedg,
                                                  const int* __restrict__ sedg,
                                                  int* __restrict__ head,
                                                  int* __restrict__ bucket) {
  __shared__ int h[NR], bb[NR];
  if (threadIdx.x < NR) h[threadIdx.x] = 0;
  __syncthreads();
  int e = blockIdx.x * 256 + threadIdx.x;
  int r = -1, pos = 0;
  if (e < ET) {
    const int* p = (e < EN) ? nedg + (size_t)e * 5 : sedg + (size_t)(e - EN) * 5;
    r = p[4];
    pos = atomicAdd(&h[r], 1);
  }
  __syncthreads();
  if (threadIdx.x < NR)
    bb[threadIdx.x] = h[threadIdx.x] ? atomicAdd(&head[threadIdx.x], h[threadIdx.x]) : 0;
  __syncthreads();
  if (r >= 0) bucket[bb[r] + pos] = e;
}

// ---------- target counting sort (100K bins, 3-kernel scan) ----------
__global__ __launch_bounds__(256) void k_thist(const int* __restrict__ nedg,
                                               const int* __restrict__ sedg,
                                               int* __restrict__ thist) {
  int e = blockIdx.x * 256 + threadIdx.x;
  if (e >= ET) return;
  const int* p = (e < EN) ? nedg + (size_t)e * 5 : sedg + (size_t)(e - EN) * 5;
  atomicAdd(&thist[p[2]], 1);
}

__global__ __launch_bounds__(256) void k_scan1(const int* __restrict__ hist,
                                               int* __restrict__ local_ex,
                                               int* __restrict__ bsum, int n) {
  __shared__ int s[256];
  int i = blockIdx.x * 256 + threadIdx.x;
  int v = (i < n) ? hist[i] : 0;
  s[threadIdx.x] = v;
  __syncthreads();
  for (int off = 1; off < 256; off <<= 1) {
    int t = (threadIdx.x >= off) ? s[threadIdx.x - off] : 0;
    __syncthreads();
    s[threadIdx.x] += t;
    __syncthreads();
  }
  if (i < n) local_ex[i] = s[threadIdx.x] - v;   // exclusive, block-local
  if (threadIdx.x == 255) bsum[blockIdx.x] = s[255];
}

__global__ __launch_bounds__(512) void k_scan2(int* __restrict__ bsum, int nb) {
  __shared__ int s[512];
  int v = (threadIdx.x < nb) ? bsum[threadIdx.x] : 0;
  s[threadIdx.x] = v;
  __syncthreads();
  for (int off = 1; off < 512; off <<= 1) {
    int t = (threadIdx.x >= off) ? s[threadIdx.x - off] : 0;
    __syncthreads();
    s[threadIdx.x] += t;
    __syncthreads();
  }
  if (threadIdx.x < nb) bsum[threadIdx.x] = s[threadIdx.x] - v;  // exclusive in place
}

__global__ void k_scan3(int* __restrict__ tgt_off, const int* __restrict__ bsum,
                        int* __restrict__ thead) {
  int i = blockIdx.x * 256 + threadIdx.x;
  if (i < NE) {
    int v = tgt_off[i] + bsum[i >> 8];
    tgt_off[i] = v;
    thead[i] = v;
  }
  if (i == 0) tgt_off[NE] = ET;
}

__global__ __launch_bounds__(256) void k_tscatter(const int* __restrict__ nedg,
                                                  const int* __restrict__ sedg,
                                                  int* __restrict__ thead,
                                                  int* __restrict__ tpos,
                                                  int* __restrict__ esorted) {
  int e = blockIdx.x * 256 + threadIdx.x;
  if (e >= ET) return;
  const int* p = (e < EN) ? nedg + (size_t)e * 5 : sedg + (size_t)(e - EN) * 5;
  int pos = atomicAdd(&thead[p[2]], 1);
  tpos[e] = pos;
  esorted[pos] = e;
}

// ---------- fused per-edge pass (per relation): intents -> iw -> score -> exp,
// msg row (scaled by exp_s) written bf16 to target-sorted position. No atomics.
__global__ __launch_bounds__(1024) void k_pass1(
    const ushort* __restrict__ entb,
    const int* __restrict__ nedg, const int* __restrict__ sedg,
    const int* __restrict__ cnt, const int* __restrict__ base_g,
    const int* __restrict__ bucket, const int* __restrict__ tpos,
    const float* __restrict__ rel_emb,
    const float* __restrict__ W_rel, const float* __restrict__ b_rel,
    const float* __restrict__ W_msg,
    const float* __restrict__ W_int, const float* __restrict__ b_int,
    const float* __restrict__ W_ibn, const float* __restrict__ b_ibn,
    ushort* __restrict__ msgbuf, float* __restrict__ exps_s) {
  const int r = blockIdx.y;
  __shared__ ushort sA[TE * D];          // 64 KB: tgt then src tile (bf16, swizzled)
  __shared__ ushort sWm[D * D];          // 32 KB: W_msg^T [n][k]
  __shared__ ushort sWr[DR * D];         // 16 KB: W_rel^T [n][k]
  __shared__ ushort sWi[NT * 16 * D];    // 12 KB: W_int^T [tt*16+j][k], rows 8..15 zero
  __shared__ float sInt[TE][NI + 1];     // padded stride 9
  __shared__ int sS[TE], sT[TE], sTT[TE], sTP[TE];
  __shared__ float sIW[TE];
  __shared__ float sbrel[DR], srele[DR];
  __shared__ float sbint[NT * NI], sWibn[NT * NI * NR], sbibn[NT * NR];

  const int tid = threadIdx.x;
  const int lane = tid & 63;
  const int wv = tid >> 6;       // 0..15
  const int g = lane >> 4;       // 0..3
  const int c = lane & 15;       // 0..15

  // ---- load weights (once per block), bf16 pairs packed as u32 ----
  const float* Wr = W_rel + (size_t)r * D * DR;
  for (int i = tid; i < (D / 2) * DR; i += 1024) {
    int k2 = i / DR, n = i % DR;
    float a = Wr[(2 * k2) * DR + n], b = Wr[(2 * k2 + 1) * DR + n];
    lds_wr2(sWr, n, 2 * k2, (uint32_t)f2b(a) | ((uint32_t)f2b(b) << 16));
  }
  const float* Wm = W_msg + (size_t)r * D * D;
  for (int i = tid; i < (D / 2) * D; i += 1024) {
    int k2 = i >> 7, n = i & 127;
    float a = Wm[(2 * k2) * D + n], b = Wm[(2 * k2 + 1) * D + n];
    lds_wr2(sWm, n, 2 * k2, (uint32_t)f2b(a) | ((uint32_t)f2b(b) << 16));
  }
  for (int i = tid; i < NT * NI * (D / 2); i += 1024) {
    int tt = i / (NI * D / 2), rem = i % (NI * D / 2), j = rem / (D / 2), k2 = rem % (D / 2);
    const float* Wi = W_int + (size_t)tt * D * NI;
    float a = Wi[(2 * k2) * NI + j], b = Wi[(2 * k2 + 1) * NI + j];
    lds_wr2(sWi, tt * 16 + j, 2 * k2, (uint32_t)f2b(a) | ((uint32_t)f2b(b) << 16));
  }
  for (int i = tid; i < NT * 8 * (D / 2); i += 1024) {
    int tt = i / (8 * D / 2), rem = i % (8 * D / 2), j = rem / (D / 2), k2 = rem % (D / 2);
    lds_wr2(sWi, tt * 16 + 8 + j, 2 * k2, 0u);
  }
  if (tid < DR) { sbrel[tid] = b_rel[r * DR + tid]; srele[tid] = rel_emb[r * DR + tid]; }
  for (int i = tid; i < NT * NI; i += 1024) sbint[i] = b_int[i];
  for (int i = tid; i < NT * NI * NR; i += 1024) sWibn[i] = W_ibn[i];
  for (int i = tid; i < NT * NR; i += 1024) sbibn[i] = b_ibn[i];

  const int nr = cnt[r];
  const int bbase = base_g[r];
  const int ntiles = (nr + TE - 1) / TE;

  for (int tile = blockIdx.x; tile < ntiles; tile += gridDim.x) {
    const int e0 = tile * TE;
    const int ne = min(TE, nr - e0);
    __syncthreads();

    // ---- edge meta ----
    int my_tt = 0;
    if (tid < TE) {
      int s = 0, t = 0, tt = 0, tp = 0;
      if (tid < ne) {
        int eg = bucket[bbase + e0 + tid];
        const int* p = (eg < EN) ? nedg + (size_t)eg * 5 : sedg + (size_t)(eg - EN) * 5;
        s = p[0]; t = p[2]; tt = p[3];
        tp = tpos[eg];
      }
      sS[tid] = s; sT[tid] = t; sTT[tid] = tt; sTP[tid] = tp;
      my_tt = tt;
    }
    __syncthreads();

    // ---- gather tgt -> sA ----
    {
      const int row = tid & 255, h = tid >> 8;
      const frag* rp = (const frag*)(entb + (size_t)sT[row] * D);
#pragma unroll
      for (int j = 0; j < 4; j++) lds_wr(sA, row, h * 4 + j, rp[h * 4 + j]);
    }
    __syncthreads();

    // ---- intent GEMM (3 types, N padded to 16) ----
    {
      f32x4 accI[NT];
#pragma unroll
      for (int tt = 0; tt < NT; tt++) accI[tt] = (f32x4){0.f, 0.f, 0.f, 0.f};
#pragma unroll
      for (int ks = 0; ks < 4; ks++) {
        const int k = ks * 32 + g * 8;
        frag a0 = lds_rd(sA, wv * 16 + c, k);
#pragma unroll
        for (int tt = 0; tt < NT; tt++) {
          frag b = lds_rd(sWi, tt * 16 + c, k);
          accI[tt] = __builtin_amdgcn_mfma_f32_16x16x32_bf16(a0, b, accI[tt], 0, 0, 0);
        }
      }
      if (c < NI) {
        const int mb = wv * 16 + g * 4;
#pragma unroll
        for (int tt = 0; tt < NT; tt++)
#pragma unroll
          for (int q = 0; q < 4; q++)
            if (sTT[mb + q] == tt) sInt[mb + q][c] = accI[tt][q];
      }
    }
    __syncthreads();

    // ---- gather src -> sA (reuse) + owner-thread softmax/iw ----
    {
      const int row = tid & 255, h = tid >> 8;
      const frag* rp = (const frag*)(entb + (size_t)sS[row] * D);
      frag tmp[4];
#pragma unroll
      for (int j = 0; j < 4; j++) tmp[j] = rp[h * 4 + j];  // loads in flight

      if (tid < ne) {
        const int tt = my_tt;
        float it[NI], mx = -1e30f;
#pragma unroll
        for (int j = 0; j < NI; j++) {
          it[j] = sInt[tid][j] + sbint[tt * NI + j];
          mx = fmaxf(mx, it[j]);
        }
        float ssum = 0.f;
#pragma unroll
        for (int j = 0; j < NI; j++) { it[j] = __expf(it[j] - mx); ssum += it[j]; }
        const float inv = 1.f / ssum;
        float qv[NR];
#pragma unroll
        for (int k = 0; k < NR; k++) qv[k] = sbibn[tt * NR + k];
#pragma unroll
        for (int j = 0; j < NI; j++) {
          const float ij = it[j] * inv;
#pragma unroll
          for (int k = 0; k < NR; k++) qv[k] = fmaf(ij, sWibn[(tt * NI + j) * NR + k], qv[k]);
        }
        float m9 = qv[0];
#pragma unroll
        for (int k = 1; k < NR; k++) m9 = fmaxf(m9, qv[k]);
        float s9 = 0.f;
#pragma unroll
        for (int k = 0; k < NR; k++) s9 += __expf(qv[k] - m9);
        sIW[tid] = __expf(qv[r] - m9) / s9;
      }
#pragma unroll
      for (int j = 0; j < 4; j++) lds_wr(sA, row, h * 4 + j, tmp[j]);
    }
    __syncthreads();

    // ---- main GEMMs: src @ W_rel (4 N-tiles) and src @ W_msg (8 N-tiles) ----
    f32x4 accR[4], accM[8];
#pragma unroll
    for (int nt = 0; nt < 4; nt++) accR[nt] = (f32x4){0.f, 0.f, 0.f, 0.f};
#pragma unroll
    for (int nt = 0; nt < 8; nt++) accM[nt] = (f32x4){0.f, 0.f, 0.f, 0.f};
#pragma unroll
    for (int ks = 0; ks < 4; ks++) {
      const int k = ks * 32 + g * 8;
      frag a0 = lds_rd(sA, wv * 16 + c, k);
#pragma unroll
      for (int nt = 0; nt < 4; nt++) {
        frag b = lds_rd(sWr, nt * 16 + c, k);
        accR[nt] = __builtin_amdgcn_mfma_f32_16x16x32_bf16(a0, b, accR[nt], 0, 0, 0);
      }
#pragma unroll
      for (int nt = 0; nt < 8; nt++) {
        frag b = lds_rd(sWm, nt * 16 + c, k);
        accM[nt] = __builtin_amdgcn_mfma_f32_16x16x32_bf16(a0, b, accM[nt], 0, 0, 0);
      }
    }

    // ---- score epilogue: selu, dot rel_e, 16-lane reduce, exp ----
    float es[4];
    {
      float v[4] = {0.f, 0.f, 0.f, 0.f};
#pragma unroll
      for (int nt = 0; nt < 4; nt++) {
        const int col = nt * 16 + c;
        const float br = sbrel[col], re = srele[col];
#pragma unroll
        for (int q = 0; q < 4; q++) {
          const float x = accR[nt][q] + br;
          const float sl = x > 0.f ? 1.0507009873554805f * x
                                   : 1.7580993408473766f * expm1f(x);
          v[q] = fmaf(sl, re, v[q]);
        }
      }
#pragma unroll
      for (int off = 1; off < 16; off <<= 1)
#pragma unroll
        for (int q = 0; q < 4; q++) v[q] += __shfl_xor(v[q], off, 64);
      const int mb = wv * 16 + g * 4;
#pragma unroll
      for (int q = 0; q < 4; q++) {
        const int m = mb + q;
        const float e_s = __expf(v[q] * sIW[m]);
        es[q] = e_s;
        if (c == 0 && m < ne) exps_s[sTP[m]] = e_s;
      }
    }

    // ---- msg write: bf16 rows (scaled by es) at target-sorted positions ----
    {
      const int mb = wv * 16 + g * 4;
#pragma unroll
      for (int q = 0; q < 4; q++) {
        const int m = mb + q;
        ushort* mrow = msgbuf + (size_t)sTP[m] * D;
#pragma unroll
        for (int nt = 0; nt < 8; nt++) {
          float val = accM[nt][q] * es[q];
          float other = __shfl_xor(val, 1, 64);
          if (!(c & 1) && m < ne) {
            uint32_t pk = (uint32_t)f2b(val) | ((uint32_t)f2b(other) << 16);
            *(uint32_t*)(mrow + nt * 16 + c) = pk;
          }
        }
      }
    }
  }
}

// ---------- per-target reduce: ent = sum(msg)/sum(es); dist scatter ----------
__global__ __launch_bounds__(256) void k_agg(
    const ushort* __restrict__ msgbuf, const float* __restrict__ exps_s,
    const int* __restrict__ tgt_off, const int* __restrict__ esorted,
    ushort* __restrict__ entb, float* __restrict__ fout,
    float* __restrict__ dout, int last) {
  const int lane = threadIdx.x & 63;
  const int wv = threadIdx.x >> 6;
  const int nw = gridDim.x * 4;
  for (int t = blockIdx.x * 4 + wv; t < NE; t += nw) {
    const int beg = tgt_off[t], end = tgt_off[t + 1];
    float a0 = 0.f, a1 = 0.f, dsum = 0.f;
    for (int j = beg; j < end; j++) {
      uint32_t pk = *(const uint32_t*)(msgbuf + (size_t)j * D + 2 * lane);
      a0 += __uint_as_float(pk << 16);
      a1 += __uint_as_float(pk & 0xFFFF0000u);
      dsum += exps_s[j];
    }
    const float rec = (dsum != 0.f) ? 1.f / dsum : 0.f;
    a0 *= rec; a1 *= rec;
    if (last) {
      ((float2*)(fout + (size_t)t * D))[lane] = make_float2(a0, a1);
    } else {
      uint32_t pk = (uint32_t)f2b(a0) | ((uint32_t)f2b(a1) << 16);
      *(uint32_t*)(entb + (size_t)t * D + 2 * lane) = pk;
    }
    for (int j = beg + lane; j < end; j += 64) dout[esorted[j]] = exps_s[j] * rec;
  }
}

extern "C" void kernel_launch(void* const* d_in, const int* in_sizes, int n_in,
                              void* d_out, int out_size, void* d_ws, size_t ws_size,
                              hipStream_t stream) {
  const int* nedg = (const int*)d_in[0];
  const int* ntypes = (const int*)d_in[1];
  const int* sedg = (const int*)d_in[2];
  const float* emb = (const float*)d_in[3];
  const float* def = (const float*)d_in[4];
  const float* rel_emb = (const float*)d_in[5];
  const float* W_rel = (const float*)d_in[6];
  const float* b_rel = (const float*)d_in[7];
  const float* W_msg = (const float*)d_in[8];
  const float* W_int = (const float*)d_in[9];
  const float* b_int = (const float*)d_in[10];
  const float* W_ibn = (const float*)d_in[11];
  const float* b_ibn = (const float*)d_in[12];
  float* out = (float*)d_out;

  char* w = (char*)d_ws;
  size_t off = 0;
  ushort* entb = (ushort*)(w + off); off += (size_t)NE * D * 2;        // 25.6 MB
  ushort* msgbuf = (ushort*)(w + off); off += (size_t)ET * D * 2;      // 65.0 MB
  float* exps_s = (float*)(w + off); off += (size_t)ET * 4;
  int* bucket = (int*)(w + off); off += (size_t)ET * 4;
  int* tpos = (int*)(w + off); off += (size_t)ET * 4;
  int* esorted = (int*)(w + off); off += (size_t)ET * 4;
  int* tgt_off = (int*)(w + off); off += (size_t)(NE + 4) * 4;
  int* thead = (int*)(w + off); off += (size_t)NE * 4;
  int* thist = (int*)(w + off); off += (size_t)NE * 4;
  int* bsum = (int*)(w + off); off += 2048;
  int* cnt = (int*)(w + off); off += 64;                                // ~95.9 MB total
  int* base_g = cnt + 16;
  int* head = cnt + 32;
  float* dist_base = out + (size_t)NE * D;

  const int eblocks = (ET + 255) / 256;
  const int nb = (NE + 255) / 256;  // 391 scan blocks

  k_init<<<dim3((NE * (D / 4) + 255) / 256), 256, 0, stream>>>(entb, ntypes, def, emb);
  k_zero_cnt<<<1, 64, 0, stream>>>(cnt);
  k_hist<<<dim3(eblocks), 256, 0, stream>>>(nedg, sedg, cnt);
  k_prefix<<<1, 64, 0, stream>>>(cnt, base_g, head);
  k_scatter2<<<dim3(eblocks), 256, 0, stream>>>(nedg, sedg, head, bucket);

  fill_zero<<<dim3((NE / 4 + 255) / 256), 256, 0, stream>>>((float4*)thist, NE / 4);
  k_thist<<<dim3(eblocks), 256, 0, stream>>>(nedg, sedg, thist);
  k_scan1<<<dim3(nb), 256, 0, stream>>>(thist, tgt_off, bsum, NE);
  k_scan2<<<1, 512, 0, stream>>>(bsum, nb);
  k_scan3<<<dim3(nb), 256, 0, stream>>>(tgt_off, bsum, thead);
  k_tscatter<<<dim3(eblocks), 256, 0, stream>>>(nedg, sedg, thead, tpos, esorted);

  for (int l = 0; l < 3; l++) {
    k_pass1<<<dim3(TILES_X, NR), 1024, 0, stream>>>(
        entb, nedg, sedg, cnt, base_g, bucket, tpos, rel_emb, W_rel, b_rel, W_msg,
        W_int, b_int, W_ibn, b_ibn, msgbuf, exps_s);
    k_agg<<<dim3(512), 256, 0, stream>>>(msgbuf, exps_s, tgt_off, esorted, entb, out,
                                         dist_base + (size_t)l * ET, l == 2);
  }
}

// Round 6
// 375.823 us; speedup vs baseline: 8.6646x; 1.4558x over previous
//
#include <hip/hip_runtime.h>
#include <cstddef>
#include <cstdint>

#define NE 100000   // entities
#define EN 4096     // new edges
#define ET 254096   // total edges
#define D 128       // D_ENT
#define DR 64       // D_REL
#define NR 9        // relations
#define NT 3        // node types
#define NI 8        // intents
#define TE 256      // edges per tile
#define TILES_X 28  // blocks per relation (252 total ~ 1/CU)

using frag  = __attribute__((ext_vector_type(8))) short;
using f32x4 = __attribute__((ext_vector_type(4))) float;

__device__ __forceinline__ ushort f2b(float x) {
  union { float f; uint32_t u; } v; v.f = x;
  uint32_t r = v.u + 0x7FFFu + ((v.u >> 16) & 1u);  // RNE
  return (ushort)(r >> 16);
}

// LDS tiles: row-major [rows][128] bf16, 16B chunks XOR-swizzled by (row&7).
__device__ __forceinline__ frag lds_rd(const ushort* b, int row, int k) {
  const int ch = ((k >> 3) ^ (row & 7));
  return *(const frag*)(b + row * D + (ch << 3));
}
__device__ __forceinline__ void lds_wr(ushort* b, int row, int ch, frag v) {
  *(frag*)(b + row * D + ((ch ^ (row & 7)) << 3)) = v;
}
__device__ __forceinline__ void lds_wr2(ushort* b, int row, int k, uint32_t v) {
  const int ch = (k >> 3) ^ (row & 7);               // k even, pair (k,k+1)
  *(uint32_t*)(b + row * D + (ch << 3) + (k & 7)) = v;
}

__global__ void fill_zero(float4* __restrict__ p, int n4) {
  int i = blockIdx.x * blockDim.x + threadIdx.x;
  if (i < n4) p[i] = make_float4(0.f, 0.f, 0.f, 0.f);
}

__global__ void k_init(ushort* __restrict__ entb, const int* __restrict__ ntypes,
                       const float* __restrict__ def, const float* __restrict__ emb) {
  int i = blockIdx.x * blockDim.x + threadIdx.x;  // one per 4 elems
  if (i >= NE * (D / 4)) return;
  int row = i >> 5, ch = i & 31;
  float4 v;
  if (row < EN) v = ((const float4*)(def + ntypes[row] * D))[ch];
  else v = ((const float4*)(emb + (size_t)(row - EN) * D))[ch];
  ushort4 h;
  h.x = f2b(v.x); h.y = f2b(v.y); h.z = f2b(v.z); h.w = f2b(v.w);
  ((ushort4*)entb)[i] = h;
}

__global__ void k_zero_cnt(int* cnt) { if (threadIdx.x < 48) cnt[threadIdx.x] = 0; }

// ---------- relation counting sort ----------
__global__ __launch_bounds__(256) void k_hist(const int* __restrict__ nedg,
                                              const int* __restrict__ sedg,
                                              int* __restrict__ cnt) {
  __shared__ int h[NR];
  if (threadIdx.x < NR) h[threadIdx.x] = 0;
  __syncthreads();
  int e = blockIdx.x * 256 + threadIdx.x;
  if (e < ET) {
    const int* p = (e < EN) ? nedg + (size_t)e * 5 : sedg + (size_t)(e - EN) * 5;
    atomicAdd(&h[p[4]], 1);
  }
  __syncthreads();
  if (threadIdx.x < NR && h[threadIdx.x]) atomicAdd(&cnt[threadIdx.x], h[threadIdx.x]);
}

__global__ void k_prefix(const int* __restrict__ cnt, int* __restrict__ base,
                         int* __restrict__ head) {
  if (threadIdx.x == 0) {
    int acc = 0;
    for (int r = 0; r < NR; r++) { base[r] = acc; head[r] = acc; acc += cnt[r]; }
  }
}

__global__ __launch_bounds__(256) void k_scatter2(const int* __restrict__ nedg,
                                                  const int* __restrict__ sedg,
                                                  int* __restrict__ head,
                                                  int* __restrict__ bucket) {
  __shared__ int h[NR], bb[NR];
  if (threadIdx.x < NR) h[threadIdx.x] = 0;
  __syncthreads();
  int e = blockIdx.x * 256 + threadIdx.x;
  int r = -1, pos = 0;
  if (e < ET) {
    const int* p = (e < EN) ? nedg + (size_t)e * 5 : sedg + (size_t)(e - EN) * 5;
    r = p[4];
    pos = atomicAdd(&h[r], 1);
  }
  __syncthreads();
  if (threadIdx.x < NR)
    bb[threadIdx.x] = h[threadIdx.x] ? atomicAdd(&head[threadIdx.x], h[threadIdx.x]) : 0;
  __syncthreads();
  if (r >= 0) bucket[bb[r] + pos] = e;
}

// ---------- target counting sort (100K bins, 3-kernel scan) ----------
__global__ __launch_bounds__(256) void k_thist(const int* __restrict__ nedg,
                                               const int* __restrict__ sedg,
                                               int* __restrict__ thist) {
  int e = blockIdx.x * 256 + threadIdx.x;
  if (e >= ET) return;
  const int* p = (e < EN) ? nedg + (size_t)e * 5 : sedg + (size_t)(e - EN) * 5;
  atomicAdd(&thist[p[2]], 1);
}

__global__ __launch_bounds__(256) void k_scan1(const int* __restrict__ hist,
                                               int* __restrict__ local_ex,
                                               int* __restrict__ bsum, int n) {
  __shared__ int s[256];
  int i = blockIdx.x * 256 + threadIdx.x;
  int v = (i < n) ? hist[i] : 0;
  s[threadIdx.x] = v;
  __syncthreads();
  for (int off = 1; off < 256; off <<= 1) {
    int t = (threadIdx.x >= off) ? s[threadIdx.x - off] : 0;
    __syncthreads();
    s[threadIdx.x] += t;
    __syncthreads();
  }
  if (i < n) local_ex[i] = s[threadIdx.x] - v;   // exclusive, block-local
  if (threadIdx.x == 255) bsum[blockIdx.x] = s[255];
}

__global__ __launch_bounds__(512) void k_scan2(int* __restrict__ bsum, int nb) {
  __shared__ int s[512];
  int v = (threadIdx.x < nb) ? bsum[threadIdx.x] : 0;
  s[threadIdx.x] = v;
  __syncthreads();
  for (int off = 1; off < 512; off <<= 1) {
    int t = (threadIdx.x >= off) ? s[threadIdx.x - off] : 0;
    __syncthreads();
    s[threadIdx.x] += t;
    __syncthreads();
  }
  if (threadIdx.x < nb) bsum[threadIdx.x] = s[threadIdx.x] - v;  // exclusive in place
}

__global__ void k_scan3(int* __restrict__ tgt_off, const int* __restrict__ bsum,
                        int* __restrict__ thead) {
  int i = blockIdx.x * 256 + threadIdx.x;
  if (i < NE) {
    int v = tgt_off[i] + bsum[i >> 8];
    tgt_off[i] = v;
    thead[i] = v;
  }
  if (i == 0) tgt_off[NE] = ET;
}

__global__ __launch_bounds__(256) void k_tscatter(const int* __restrict__ nedg,
                                                  const int* __restrict__ sedg,
                                                  int* __restrict__ thead,
                                                  int* __restrict__ tpos,
                                                  int* __restrict__ esorted) {
  int e = blockIdx.x * 256 + threadIdx.x;
  if (e >= ET) return;
  const int* p = (e < EN) ? nedg + (size_t)e * 5 : sedg + (size_t)(e - EN) * 5;
  int pos = atomicAdd(&thead[p[2]], 1);
  tpos[e] = pos;
  esorted[pos] = e;
}

// ---------- fused per-edge pass (per relation): intents -> iw -> score -> exp,
// msg row (scaled by exp_s) written bf16 to target-sorted position. No atomics.
__global__ __launch_bounds__(1024) void k_pass1(
    const ushort* __restrict__ entb,
    const int* __restrict__ nedg, const int* __restrict__ sedg,
    const int* __restrict__ cnt, const int* __restrict__ base_g,
    const int* __restrict__ bucket, const int* __restrict__ tpos,
    const float* __restrict__ rel_emb,
    const float* __restrict__ W_rel, const float* __restrict__ b_rel,
    const float* __restrict__ W_msg,
    const float* __restrict__ W_int, const float* __restrict__ b_int,
    const float* __restrict__ W_ibn, const float* __restrict__ b_ibn,
    ushort* __restrict__ msgbuf, float* __restrict__ exps_s) {
  const int r = blockIdx.y;
  __shared__ ushort sA[TE * D];          // 64 KB: tgt then src tile (bf16, swizzled)
  __shared__ ushort sWm[D * D];          // 32 KB: W_msg^T [n][k]
  __shared__ ushort sWr[DR * D];         // 16 KB: W_rel^T [n][k]
  __shared__ ushort sWi[NT * 16 * D];    // 12 KB: W_int^T [tt*16+j][k], rows 8..15 zero
  __shared__ float sInt[TE][NI + 1];     // padded stride 9
  __shared__ int sS[TE], sT[TE], sTT[TE], sTP[TE];
  __shared__ float sIW[TE];
  __shared__ float sbrel[DR], srele[DR];
  __shared__ float sbint[NT * NI], sWibn[NT * NI * NR], sbibn[NT * NR];

  const int tid = threadIdx.x;
  const int lane = tid & 63;
  const int wv = tid >> 6;       // 0..15
  const int g = lane >> 4;       // 0..3
  const int c = lane & 15;       // 0..15

  // ---- load weights (once per block), bf16 pairs packed as u32 ----
  const float* Wr = W_rel + (size_t)r * D * DR;
  for (int i = tid; i < (D / 2) * DR; i += 1024) {
    int k2 = i / DR, n = i % DR;
    float a = Wr[(2 * k2) * DR + n], b = Wr[(2 * k2 + 1) * DR + n];
    lds_wr2(sWr, n, 2 * k2, (uint32_t)f2b(a) | ((uint32_t)f2b(b) << 16));
  }
  const float* Wm = W_msg + (size_t)r * D * D;
  for (int i = tid; i < (D / 2) * D; i += 1024) {
    int k2 = i >> 7, n = i & 127;
    float a = Wm[(2 * k2) * D + n], b = Wm[(2 * k2 + 1) * D + n];
    lds_wr2(sWm, n, 2 * k2, (uint32_t)f2b(a) | ((uint32_t)f2b(b) << 16));
  }
  for (int i = tid; i < NT * NI * (D / 2); i += 1024) {
    int tt = i / (NI * D / 2), rem = i % (NI * D / 2), j = rem / (D / 2), k2 = rem % (D / 2);
    const float* Wi = W_int + (size_t)tt * D * NI;
    float a = Wi[(2 * k2) * NI + j], b = Wi[(2 * k2 + 1) * NI + j];
    lds_wr2(sWi, tt * 16 + j, 2 * k2, (uint32_t)f2b(a) | ((uint32_t)f2b(b) << 16));
  }
  for (int i = tid; i < NT * 8 * (D / 2); i += 1024) {
    int tt = i / (8 * D / 2), rem = i % (8 * D / 2), j = rem / (D / 2), k2 = rem % (D / 2);
    lds_wr2(sWi, tt * 16 + 8 + j, 2 * k2, 0u);
  }
  if (tid < DR) { sbrel[tid] = b_rel[r * DR + tid]; srele[tid] = rel_emb[r * DR + tid]; }
  for (int i = tid; i < NT * NI; i += 1024) sbint[i] = b_int[i];
  for (int i = tid; i < NT * NI * NR; i += 1024) sWibn[i] = W_ibn[i];
  for (int i = tid; i < NT * NR; i += 1024) sbibn[i] = b_ibn[i];

  const int nr = cnt[r];
  const int bbase = base_g[r];
  const int ntiles = (nr + TE - 1) / TE;

  for (int tile = blockIdx.x; tile < ntiles; tile += gridDim.x) {
    const int e0 = tile * TE;
    const int ne = min(TE, nr - e0);
    __syncthreads();

    // ---- edge meta ----
    int my_tt = 0;
    if (tid < TE) {
      int s = 0, t = 0, tt = 0, tp = 0;
      if (tid < ne) {
        int eg = bucket[bbase + e0 + tid];
        const int* p = (eg < EN) ? nedg + (size_t)eg * 5 : sedg + (size_t)(eg - EN) * 5;
        s = p[0]; t = p[2]; tt = p[3];
        tp = tpos[eg];
      }
      sS[tid] = s; sT[tid] = t; sTT[tid] = tt; sTP[tid] = tp;
      my_tt = tt;
    }
    __syncthreads();

    // ---- gather tgt -> sA ----
    {
      const int row = tid & 255, h = tid >> 8;
      const frag* rp = (const frag*)(entb + (size_t)sT[row] * D);
#pragma unroll
      for (int j = 0; j < 4; j++) lds_wr(sA, row, h * 4 + j, rp[h * 4 + j]);
    }
    __syncthreads();

    // ---- intent GEMM (3 types, N padded to 16) ----
    {
      f32x4 accI[NT];
#pragma unroll
      for (int tt = 0; tt < NT; tt++) accI[tt] = (f32x4){0.f, 0.f, 0.f, 0.f};
#pragma unroll
      for (int ks = 0; ks < 4; ks++) {
        const int k = ks * 32 + g * 8;
        frag a0 = lds_rd(sA, wv * 16 + c, k);
#pragma unroll
        for (int tt = 0; tt < NT; tt++) {
          frag b = lds_rd(sWi, tt * 16 + c, k);
          accI[tt] = __builtin_amdgcn_mfma_f32_16x16x32_bf16(a0, b, accI[tt], 0, 0, 0);
        }
      }
      if (c < NI) {
        const int mb = wv * 16 + g * 4;
#pragma unroll
        for (int tt = 0; tt < NT; tt++)
#pragma unroll
          for (int q = 0; q < 4; q++)
            if (sTT[mb + q] == tt) sInt[mb + q][c] = accI[tt][q];
      }
    }
    __syncthreads();

    // ---- gather src -> sA (reuse) + owner-thread softmax/iw ----
    {
      const int row = tid & 255, h = tid >> 8;
      const frag* rp = (const frag*)(entb + (size_t)sS[row] * D);
      frag tmp[4];
#pragma unroll
      for (int j = 0; j < 4; j++) tmp[j] = rp[h * 4 + j];  // loads in flight

      if (tid < ne) {
        const int tt = my_tt;
        float it[NI], mx = -1e30f;
#pragma unroll
        for (int j = 0; j < NI; j++) {
          it[j] = sInt[tid][j] + sbint[tt * NI + j];
          mx = fmaxf(mx, it[j]);
        }
        float ssum = 0.f;
#pragma unroll
        for (int j = 0; j < NI; j++) { it[j] = __expf(it[j] - mx); ssum += it[j]; }
        const float inv = 1.f / ssum;
        float qv[NR];
#pragma unroll
        for (int k = 0; k < NR; k++) qv[k] = sbibn[tt * NR + k];
#pragma unroll
        for (int j = 0; j < NI; j++) {
          const float ij = it[j] * inv;
#pragma unroll
          for (int k = 0; k < NR; k++) qv[k] = fmaf(ij, sWibn[(tt * NI + j) * NR + k], qv[k]);
        }
        float m9 = qv[0];
#pragma unroll
        for (int k = 1; k < NR; k++) m9 = fmaxf(m9, qv[k]);
        float s9 = 0.f;
#pragma unroll
        for (int k = 0; k < NR; k++) s9 += __expf(qv[k] - m9);
        sIW[tid] = __expf(qv[r] - m9) / s9;
      }
#pragma unroll
      for (int j = 0; j < 4; j++) lds_wr(sA, row, h * 4 + j, tmp[j]);
    }
    __syncthreads();

    // ---- main GEMMs: src @ W_rel (4 N-tiles) and src @ W_msg (8 N-tiles) ----
    f32x4 accR[4], accM[8];
#pragma unroll
    for (int nt = 0; nt < 4; nt++) accR[nt] = (f32x4){0.f, 0.f, 0.f, 0.f};
#pragma unroll
    for (int nt = 0; nt < 8; nt++) accM[nt] = (f32x4){0.f, 0.f, 0.f, 0.f};
#pragma unroll
    for (int ks = 0; ks < 4; ks++) {
      const int k = ks * 32 + g * 8;
      frag a0 = lds_rd(sA, wv * 16 + c, k);
#pragma unroll
      for (int nt = 0; nt < 4; nt++) {
        frag b = lds_rd(sWr, nt * 16 + c, k);
        accR[nt] = __builtin_amdgcn_mfma_f32_16x16x32_bf16(a0, b, accR[nt], 0, 0, 0);
      }
#pragma unroll
      for (int nt = 0; nt < 8; nt++) {
        frag b = lds_rd(sWm, nt * 16 + c, k);
        accM[nt] = __builtin_amdgcn_mfma_f32_16x16x32_bf16(a0, b, accM[nt], 0, 0, 0);
      }
    }

    // ---- score epilogue: selu, dot rel_e, 16-lane reduce, exp ----
    float es[4];
    {
      float v[4] = {0.f, 0.f, 0.f, 0.f};
#pragma unroll
      for (int nt = 0; nt < 4; nt++) {
        const int col = nt * 16 + c;
        const float br = sbrel[col], re = srele[col];
#pragma unroll
        for (int q = 0; q < 4; q++) {
          const float x = accR[nt][q] + br;
          const float sl = x > 0.f ? 1.0507009873554805f * x
                                   : 1.7580993408473766f * expm1f(x);
          v[q] = fmaf(sl, re, v[q]);
        }
      }
#pragma unroll
      for (int off = 1; off < 16; off <<= 1)
#pragma unroll
        for (int q = 0; q < 4; q++) v[q] += __shfl_xor(v[q], off, 64);
      const int mb = wv * 16 + g * 4;
#pragma unroll
      for (int q = 0; q < 4; q++) {
        const int m = mb + q;
        const float e_s = __expf(v[q] * sIW[m]);
        es[q] = e_s;
        if (c == 0 && m < ne) exps_s[sTP[m]] = e_s;
      }
    }

    // ---- msg write: bf16 rows (scaled by es) at target-sorted positions ----
    {
      const int mb = wv * 16 + g * 4;
#pragma unroll
      for (int q = 0; q < 4; q++) {
        const int m = mb + q;
        ushort* mrow = msgbuf + (size_t)sTP[m] * D;
#pragma unroll
        for (int nt = 0; nt < 8; nt++) {
          float val = accM[nt][q] * es[q];
          float other = __shfl_xor(val, 1, 64);
          if (!(c & 1) && m < ne) {
            uint32_t pk = (uint32_t)f2b(val) | ((uint32_t)f2b(other) << 16);
            *(uint32_t*)(mrow + nt * 16 + c) = pk;
          }
        }
      }
    }
  }
}

// ---------- per-target reduce: 16-lane group per target, dwordx4 row loads.
// ent = sum(msg)/sum(es); dist scatter.
__global__ __launch_bounds__(256) void k_agg(
    const ushort* __restrict__ msgbuf, const float* __restrict__ exps_s,
    const int* __restrict__ tgt_off, const int* __restrict__ esorted,
    ushort* __restrict__ entb, float* __restrict__ fout,
    float* __restrict__ dout, int last) {
  const int lg = threadIdx.x & 15;    // lane in group: 8 columns each
  const int grp = threadIdx.x >> 4;   // 16 groups per block
  const int ngrp = gridDim.x * 16;
  for (int t = blockIdx.x * 16 + grp; t < NE; t += ngrp) {
    const int beg = tgt_off[t], end = tgt_off[t + 1];
    float a[8] = {0.f, 0.f, 0.f, 0.f, 0.f, 0.f, 0.f, 0.f};
    float dsum = 0.f;
    for (int j = beg; j < end; j++) {
      const uint4 pk = *(const uint4*)(msgbuf + (size_t)j * D + lg * 8);
      dsum += exps_s[j];
      a[0] += __uint_as_float(pk.x << 16); a[1] += __uint_as_float(pk.x & 0xFFFF0000u);
      a[2] += __uint_as_float(pk.y << 16); a[3] += __uint_as_float(pk.y & 0xFFFF0000u);
      a[4] += __uint_as_float(pk.z << 16); a[5] += __uint_as_float(pk.z & 0xFFFF0000u);
      a[6] += __uint_as_float(pk.w << 16); a[7] += __uint_as_float(pk.w & 0xFFFF0000u);
    }
    const float rec = (dsum != 0.f) ? 1.f / dsum : 0.f;
#pragma unroll
    for (int i = 0; i < 8; i++) a[i] *= rec;
    if (last) {
      float4* o = (float4*)(fout + (size_t)t * D + lg * 8);
      o[0] = make_float4(a[0], a[1], a[2], a[3]);
      o[1] = make_float4(a[4], a[5], a[6], a[7]);
    } else {
      uint4 pk;
      pk.x = (uint32_t)f2b(a[0]) | ((uint32_t)f2b(a[1]) << 16);
      pk.y = (uint32_t)f2b(a[2]) | ((uint32_t)f2b(a[3]) << 16);
      pk.z = (uint32_t)f2b(a[4]) | ((uint32_t)f2b(a[5]) << 16);
      pk.w = (uint32_t)f2b(a[6]) | ((uint32_t)f2b(a[7]) << 16);
      *(uint4*)(entb + (size_t)t * D + lg * 8) = pk;
    }
    for (int j = beg + lg; j < end; j += 16) dout[esorted[j]] = exps_s[j] * rec;
  }
}

extern "C" void kernel_launch(void* const* d_in, const int* in_sizes, int n_in,
                              void* d_out, int out_size, void* d_ws, size_t ws_size,
                              hipStream_t stream) {
  const int* nedg = (const int*)d_in[0];
  const int* ntypes = (const int*)d_in[1];
  const int* sedg = (const int*)d_in[2];
  const float* emb = (const float*)d_in[3];
  const float* def = (const float*)d_in[4];
  const float* rel_emb = (const float*)d_in[5];
  const float* W_rel = (const float*)d_in[6];
  const float* b_rel = (const float*)d_in[7];
  const float* W_msg = (const float*)d_in[8];
  const float* W_int = (const float*)d_in[9];
  const float* b_int = (const float*)d_in[10];
  const float* W_ibn = (const float*)d_in[11];
  const float* b_ibn = (const float*)d_in[12];
  float* out = (float*)d_out;

  char* w = (char*)d_ws;
  size_t off = 0;
  ushort* entb = (ushort*)(w + off); off += (size_t)NE * D * 2;        // 25.6 MB
  ushort* msgbuf = (ushort*)(w + off); off += (size_t)ET * D * 2;      // 65.0 MB
  float* exps_s = (float*)(w + off); off += (size_t)ET * 4;
  int* bucket = (int*)(w + off); off += (size_t)ET * 4;
  int* tpos = (int*)(w + off); off += (size_t)ET * 4;
  int* esorted = (int*)(w + off); off += (size_t)ET * 4;
  int* tgt_off = (int*)(w + off); off += (size_t)(NE + 4) * 4;
  int* thead = (int*)(w + off); off += (size_t)NE * 4;
  int* thist = (int*)(w + off); off += (size_t)NE * 4;
  int* bsum = (int*)(w + off); off += 2048;
  int* cnt = (int*)(w + off); off += 64;                                // ~95.9 MB total
  int* base_g = cnt + 16;
  int* head = cnt + 32;
  float* dist_base = out + (size_t)NE * D;

  const int eblocks = (ET + 255) / 256;
  const int nb = (NE + 255) / 256;  // 391 scan blocks

  k_init<<<dim3((NE * (D / 4) + 255) / 256), 256, 0, stream>>>(entb, ntypes, def, emb);
  k_zero_cnt<<<1, 64, 0, stream>>>(cnt);
  k_hist<<<dim3(eblocks), 256, 0, stream>>>(nedg, sedg, cnt);
  k_prefix<<<1, 64, 0, stream>>>(cnt, base_g, head);
  k_scatter2<<<dim3(eblocks), 256, 0, stream>>>(nedg, sedg, head, bucket);

  fill_zero<<<dim3((NE / 4 + 255) / 256), 256, 0, stream>>>((float4*)thist, NE / 4);
  k_thist<<<dim3(eblocks), 256, 0, stream>>>(nedg, sedg, thist);
  k_scan1<<<dim3(nb), 256, 0, stream>>>(thist, tgt_off, bsum, NE);
  k_scan2<<<1, 512, 0, stream>>>(bsum, nb);
  k_scan3<<<dim3(nb), 256, 0, stream>>>(tgt_off, bsum, thead);
  k_tscatter<<<dim3(eblocks), 256, 0, stream>>>(nedg, sedg, thead, tpos, esorted);

  for (int l = 0; l < 3; l++) {
    k_pass1<<<dim3(TILES_X, NR), 1024, 0, stream>>>(
        entb, nedg, sedg, cnt, base_g, bucket, tpos, rel_emb, W_rel, b_rel, W_msg,
        W_int, b_int, W_ibn, b_ibn, msgbuf, exps_s);
    k_agg<<<dim3(2048), 256, 0, stream>>>(msgbuf, exps_s, tgt_off, esorted, entb, out,
                                          dist_base + (size_t)l * ET, l == 2);
  }
}